// Round 1
// baseline (1701.392 us; speedup 1.0000x reference)
//
#include <hip/hip_runtime.h>
#include <cstdint>
#include <cstddef>

// ---------------------------------------------------------------------------
// HierarchicalNetwork: 2-layer Bayesian transformer decoder + mixture heads.
// B=512 L=128 D=128 H=4 dk=32 DFF=256 T=2048
// All randomness = JAX threefry2x32, fold_in(key(42), c) for c=0..45,
// partitionable random_bits (bits[i] = o0^o1 of threefry(key, 0, i)).
// Flip JAX_PARTITIONABLE to 0 if absmax shows RNG mismatch (legacy pair mode).
// ---------------------------------------------------------------------------

#ifndef JAX_PARTITIONABLE
#define JAX_PARTITIONABLE 1
#endif

#define NB   512
#define NL   128
#define ND   128
#define NH   4
#define NDFF 256
#define NT   2048
#define BL   (NB * NL)          // 65536 rows

// ----------------------------- threefry2x32 --------------------------------
__host__ __device__ __forceinline__ void tf2x32(uint32_t k0, uint32_t k1,
                                                uint32_t x0, uint32_t x1,
                                                uint32_t& o0, uint32_t& o1)
{
  const uint32_t ks2 = k0 ^ k1 ^ 0x1BD11BDAu;
  x0 += k0; x1 += k1;
#define TF_RND(r) { x0 += x1; x1 = (x1 << (r)) | (x1 >> (32 - (r))); x1 ^= x0; }
  TF_RND(13) TF_RND(15) TF_RND(26) TF_RND(6)
  x0 += k1;  x1 += ks2 + 1u;
  TF_RND(17) TF_RND(29) TF_RND(16) TF_RND(24)
  x0 += ks2; x1 += k0 + 2u;
  TF_RND(13) TF_RND(15) TF_RND(26) TF_RND(6)
  x0 += k0;  x1 += k1 + 3u;
  TF_RND(17) TF_RND(29) TF_RND(16) TF_RND(24)
  x0 += k1;  x1 += ks2 + 4u;
  TF_RND(13) TF_RND(15) TF_RND(26) TF_RND(6)
  x0 += ks2; x1 += k0 + 5u;
#undef TF_RND
  o0 = x0; o1 = x1;
}

// XLA f32 erfinv (Giles polynomial, w = -log1p(-x*x)).
// _rn intrinsics prevent -ffp-contract=fast from fusing mul+add (XLA CPU does
// separate roundings).
__device__ __forceinline__ float erfinv32(float x)
{
  float w = -log1pf(-__fmul_rn(x, x));
  float p;
  if (w < 5.0f) {
    w = w - 2.5f;
    p = 2.81022636e-08f;
    p = __fadd_rn( 3.43273939e-07f, __fmul_rn(p, w));
    p = __fadd_rn(-3.5233877e-06f,  __fmul_rn(p, w));
    p = __fadd_rn(-4.39150654e-06f, __fmul_rn(p, w));
    p = __fadd_rn( 0.00021858087f,  __fmul_rn(p, w));
    p = __fadd_rn(-0.00125372503f,  __fmul_rn(p, w));
    p = __fadd_rn(-0.00417768164f,  __fmul_rn(p, w));
    p = __fadd_rn( 0.246640727f,    __fmul_rn(p, w));
    p = __fadd_rn( 1.50140941f,     __fmul_rn(p, w));
  } else {
    w = sqrtf(w) - 3.0f;
    p = -0.000200214257f;
    p = __fadd_rn( 0.000100950558f, __fmul_rn(p, w));
    p = __fadd_rn( 0.00134934322f,  __fmul_rn(p, w));
    p = __fadd_rn(-0.00367342844f,  __fmul_rn(p, w));
    p = __fadd_rn( 0.00573950773f,  __fmul_rn(p, w));
    p = __fadd_rn(-0.0076224613f,   __fmul_rn(p, w));
    p = __fadd_rn( 0.00943887047f,  __fmul_rn(p, w));
    p = __fadd_rn( 1.00167406f,     __fmul_rn(p, w));
    p = __fadd_rn( 2.83297682f,     __fmul_rn(p, w));
  }
  return __fmul_rn(p, x);
}

// jax.random.normal bit transform: u = max(lo, f*2.0 + lo); n = sqrt2*erfinv(u)
// (hi - lo rounds to exactly 2.0f; mul by 2 is exact, add rounds once -> u
// is bit-identical to XLA's mul-then-add.)
__device__ __forceinline__ float bits_to_normal(uint32_t bits)
{
  const float lo = -0.99999994f;                 // nextafter(-1, 0)
  float f = __uint_as_float((bits >> 9) | 0x3F800000u) - 1.0f;
  float u = __fadd_rn(__fmul_rn(f, 2.0f), lo);
  u = fmaxf(lo, u);
  return __fmul_rn(1.41421356f, erfinv32(u));    // 0x3FB504F3 = f32(sqrt(2))
}

__device__ __forceinline__ float jax_normal_idx(uint32_t k0, uint32_t k1,
                                                uint32_t idx, uint32_t n)
{
  uint32_t o0, o1;
#if JAX_PARTITIONABLE
  (void)n;
  tf2x32(k0, k1, 0u, idx, o0, o1);
  return bits_to_normal(o0 ^ o1);
#else
  // legacy: counts = iota(n) (pad to even), split halves, per-pair threefry
  uint32_t h = (n + 1u) >> 1;
  if (idx < h) {
    uint32_t x1 = (idx + h < n) ? (idx + h) : 0u;
    tf2x32(k0, k1, idx, x1, o0, o1);
    return bits_to_normal(o0);
  } else {
    tf2x32(k0, k1, idx - h, idx, o0, o1);
    return bits_to_normal(o1);
  }
#endif
}

// --------------------------- sampling kernel -------------------------------
// out[i] = mu[i] + exp(ls[i]) * N_i   (Bayesian weight/bias realization)
__global__ __launch_bounds__(256) void sample_kernel(
    const float* __restrict__ mu, const float* __restrict__ ls,
    float* __restrict__ out, int n, uint32_t k0, uint32_t k1)
{
  int i = blockIdx.x * 256 + threadIdx.x;
  if (i >= n) return;
  out[i] = mu[i] + expf(ls[i]) * jax_normal_idx(k0, k1, (uint32_t)i, (uint32_t)n);
}

// --------------------------- embedding + pos-enc ---------------------------
__global__ __launch_bounds__(256) void embed_pe_kernel(
    const int* __restrict__ ev, const int* __restrict__ mask,
    const float* __restrict__ emb, float* __restrict__ X, float* __restrict__ INPX)
{
  int i = blockIdx.x * 256 + threadIdx.x;
  if (i >= BL * ND) return;
  int d  = i & (ND - 1);
  int bl = i >> 7;
  int e  = ev[bl];
  int mk = mask[bl];
  float x   = emb[(size_t)e * ND + d];
  float div = expf((float)d * (float)(-9.210340371976184 / 128.0)); // -ln(1e4)/D
  float ang = (float)mk * div;
  float pe  = ((mk & 1) == 0) ? sinf(ang) : cosf(ang);
  X[i]    = x;
  INPX[i] = x + pe;
}

// ------------------------------- GEMM (NT) ---------------------------------
// C[M,N] = act(A[M,K](lda) @ W[N,K]^T + bias[N]); M%64==N%64==K%16==0
__global__ __launch_bounds__(256) void gemm_nt(
    const float* __restrict__ A, int lda,
    const float* __restrict__ W, const float* __restrict__ bias,
    float* __restrict__ C, int M, int N, int K, int act)
{
  __shared__ float As[16][64];
  __shared__ float Ws[16][64];
  const int tid = threadIdx.x;
  const int bm = blockIdx.y * 64;
  const int bn = blockIdx.x * 64;
  const int tr = tid >> 4, tc = tid & 15;          // 16x16 thread tile
  const int lr = tid >> 2, lc = (tid & 3) << 2;    // loader: float4 per thread
  float acc[4][4] = {{0.f}};

  for (int k0 = 0; k0 < K; k0 += 16) {
    float4 av = *(const float4*)(A + (size_t)(bm + lr) * lda + k0 + lc);
    float4 wv = *(const float4*)(W + (size_t)(bn + lr) * K   + k0 + lc);
    As[lc + 0][lr] = av.x; As[lc + 1][lr] = av.y;
    As[lc + 2][lr] = av.z; As[lc + 3][lr] = av.w;
    Ws[lc + 0][lr] = wv.x; Ws[lc + 1][lr] = wv.y;
    Ws[lc + 2][lr] = wv.z; Ws[lc + 3][lr] = wv.w;
    __syncthreads();
#pragma unroll
    for (int kk = 0; kk < 16; ++kk) {
      float a[4], w[4];
#pragma unroll
      for (int i = 0; i < 4; ++i) a[i] = As[kk][(tr << 2) + i];
#pragma unroll
      for (int j = 0; j < 4; ++j) w[j] = Ws[kk][(tc << 2) + j];
#pragma unroll
      for (int i = 0; i < 4; ++i)
#pragma unroll
        for (int j = 0; j < 4; ++j)
          acc[i][j] = fmaf(a[i], w[j], acc[i][j]);
    }
    __syncthreads();
  }

#pragma unroll
  for (int i = 0; i < 4; ++i) {
    int row = bm + (tr << 2) + i;
    int col = bn + (tc << 2);
    float4 o;
    o.x = acc[i][0] + bias[col + 0];
    o.y = acc[i][1] + bias[col + 1];
    o.z = acc[i][2] + bias[col + 2];
    o.w = acc[i][3] + bias[col + 3];
    if (act == 1) {
      o.x = fmaxf(o.x, 0.f); o.y = fmaxf(o.y, 0.f);
      o.z = fmaxf(o.z, 0.f); o.w = fmaxf(o.w, 0.f);
    }
    *(float4*)(C + (size_t)row * N + col) = o;
  }
}

// ------------------------------ attention ----------------------------------
// One block per (b, head). Full 128x128 attention, dk=32, softmax with max-sub.
// Inputs in (B,L,D) layout (head slice at hh*32); output written same layout.
__global__ __launch_bounds__(256) void attn_kernel(
    const float* __restrict__ Qb, const float* __restrict__ Kb,
    const float* __restrict__ Vb, float* __restrict__ O)
{
  const int bh = blockIdx.x;
  const int b = bh >> 2, hh = bh & 3;
  __shared__ float Qs[128][32];   // broadcast reads -> no pad needed
  __shared__ float Ks[128][33];   // pad: lanes read rows -> conflict-free
  __shared__ float Vs[128][33];
  __shared__ float prow[4][128];

  const size_t base = (size_t)b * NL * ND + hh * 32;
  for (int e = threadIdx.x; e < 128 * 32; e += 256) {
    int l = e >> 5, d = e & 31;
    size_t g = base + (size_t)l * ND + d;
    Qs[l][d] = Qb[g];
    Ks[l][d] = Kb[g];
    Vs[l][d] = Vb[g];
  }
  __syncthreads();

  const int wave = threadIdx.x >> 6, lane = threadIdx.x & 63;
  const float scale = 0.1767766952966369f;   // 1/sqrt(32)

  for (int r = 0; r < 32; ++r) {
    const int row = wave * 32 + r;
    float s0 = 0.f, s1 = 0.f;
#pragma unroll
    for (int d = 0; d < 32; ++d) {
      float q = Qs[row][d];
      s0 = fmaf(q, Ks[lane][d], s0);
      s1 = fmaf(q, Ks[lane + 64][d], s1);
    }
    s0 *= scale; s1 *= scale;
    float m = fmaxf(s0, s1);
#pragma unroll
    for (int o = 32; o; o >>= 1) m = fmaxf(m, __shfl_xor(m, o));
    float p0 = expf(s0 - m), p1 = expf(s1 - m);
    float ssum = p0 + p1;
#pragma unroll
    for (int o = 32; o; o >>= 1) ssum += __shfl_xor(ssum, o);
    float inv = 1.0f / ssum;
    prow[wave][lane]      = p0 * inv;
    prow[wave][lane + 64] = p1 * inv;
    // PV: lanes 0-31 handle k in [0,64), lanes 32-63 handle [64,128), same d
    const int d  = lane & 31;
    const int k0 = (lane & 32) << 1;
    float acc = 0.f;
#pragma unroll
    for (int kk = 0; kk < 64; ++kk)
      acc = fmaf(prow[wave][k0 + kk], Vs[k0 + kk][d], acc);
    acc += __shfl_xor(acc, 32);
    if (lane < 32) O[base + (size_t)row * ND + d] = acc;
  }
}

// -------------------------- residual + layernorm ---------------------------
__global__ __launch_bounds__(128) void add_ln_kernel(
    float* __restrict__ x, const float* __restrict__ a,
    const float* __restrict__ g, const float* __restrict__ bb)
{
  const int row = blockIdx.x;
  const int t = threadIdx.x;
  const size_t off = (size_t)row * ND + t;
  float v = x[off] + a[off];
  float s = v;
#pragma unroll
  for (int o = 32; o; o >>= 1) s += __shfl_xor(s, o);
  __shared__ float red[4];
  if ((t & 63) == 0) red[t >> 6] = s;
  __syncthreads();
  float mean = (red[0] + red[1]) * (1.0f / 128.0f);
  float d = v - mean;
  float q = d * d;
#pragma unroll
  for (int o = 32; o; o >>= 1) q += __shfl_xor(q, o);
  if ((t & 63) == 0) red[2 + (t >> 6)] = q;
  __syncthreads();
  float var = (red[2] + red[3]) * (1.0f / 128.0f);
  x[off] = d / sqrtf(var + 1e-5f) * g[t] + bb[t];
}

// ------------------------------ event head ---------------------------------
// event_pred[b,t] = sum_k softmax_k(LA[b,k,t]) * (MB[b,k,t] + exp(SB[b,k,t])*noise)
__global__ __launch_bounds__(256) void event_head_kernel(
    const float* __restrict__ LA, const float* __restrict__ MB,
    const float* __restrict__ SB, float* __restrict__ out,
    uint32_t k0, uint32_t k1)
{
  int i = blockIdx.x * 256 + threadIdx.x;        // over B*T
  if (i >= NB * NT) return;
  int b = i >> 11, t = i & (NT - 1);
  size_t base = (size_t)b * (5 * NT) + t;
  float lg[5];
  float mx = -1e30f;
#pragma unroll
  for (int k = 0; k < 5; ++k) { lg[k] = LA[base + (size_t)k * NT]; mx = fmaxf(mx, lg[k]); }
  float se = 0.f;
#pragma unroll
  for (int k = 0; k < 5; ++k) { lg[k] = expf(lg[k] - mx); se += lg[k]; }
  float inv = 1.0f / se;
  float acc = 0.f;
#pragma unroll
  for (int k = 0; k < 5; ++k) {
    float nz = jax_normal_idx(k0, k1, (uint32_t)((b * 5 + k) * NT + t),
                              (uint32_t)(NB * 5 * NT));
    float mean = MB[base + (size_t)k * NT];
    float sd   = expf(SB[base + (size_t)k * NT]);
    acc += (lg[k] * inv) * (mean + sd * nz);
  }
  out[i] = acc;
}

// ------------------------------- time head ---------------------------------
__global__ __launch_bounds__(256) void time_head_kernel(
    const float* __restrict__ X, const float* __restrict__ atw,
    const float* __restrict__ atb, const float* __restrict__ tmw,
    const float* __restrict__ tmb, const float* __restrict__ tsw,
    const float* __restrict__ tsb, float* __restrict__ out,
    uint32_t k0, uint32_t k1)
{
  int b = blockIdx.x * 256 + threadIdx.x;
  if (b >= NB) return;
  const float* h = X + (size_t)b * (NL * ND);    // x[b, 0, :]
  float lg[5], tm[5], tsl[5];
  for (int k = 0; k < 5; ++k) {
    float s0 = 0.f, s1 = 0.f, s2 = 0.f;
    for (int d = 0; d < ND; ++d) {
      float hv = h[d];
      s0 = fmaf(hv, atw[k * ND + d], s0);
      s1 = fmaf(hv, tmw[k * ND + d], s1);
      s2 = fmaf(hv, tsw[k * ND + d], s2);
    }
    lg[k] = s0 + atb[k];
    tm[k] = s1 + tmb[k];
    tsl[k] = s2 + tsb[k];
  }
  float mx = lg[0];
  for (int k = 1; k < 5; ++k) mx = fmaxf(mx, lg[k]);
  float se = 0.f;
  for (int k = 0; k < 5; ++k) { lg[k] = expf(lg[k] - mx); se += lg[k]; }
  float acc = 0.f;
  for (int k = 0; k < 5; ++k) {
    float nz = jax_normal_idx(k0, k1, (uint32_t)(b * 5 + k), (uint32_t)(NB * 5));
    acc += (lg[k] / se) * (tm[k] + expf(tsl[k]) * nz);
  }
  out[b] = acc;
}

// ------------------------------ host driver --------------------------------
extern "C" void kernel_launch(void* const* d_in, const int* in_sizes, int n_in,
                              void* d_out, int out_size, void* d_ws, size_t ws_size,
                              hipStream_t stream)
{
  (void)in_sizes; (void)n_in; (void)out_size; (void)ws_size;

  const int*   ev      = (const int*)d_in[0];
  const int*   mask    = (const int*)d_in[2];
  const float* emb     = (const float*)d_in[4];
  const float* dec_wmu = (const float*)d_in[5];
  const float* dec_wls = (const float*)d_in[6];
  const float* dec_bmu = (const float*)d_in[7];
  const float* dec_bls = (const float*)d_in[8];
  const float* f1_wmu  = (const float*)d_in[9];
  const float* f1_wls  = (const float*)d_in[10];
  const float* f1_bmu  = (const float*)d_in[11];
  const float* f1_bls  = (const float*)d_in[12];
  const float* f2_wmu  = (const float*)d_in[13];
  const float* f2_wls  = (const float*)d_in[14];
  const float* f2_bmu  = (const float*)d_in[15];
  const float* f2_bls  = (const float*)d_in[16];
  const float* ln_g    = (const float*)d_in[17];
  const float* ln_b    = (const float*)d_in[18];
  const float* a_wmu   = (const float*)d_in[19];
  const float* a_wls   = (const float*)d_in[20];
  const float* a_bmu   = (const float*)d_in[21];
  const float* a_bls   = (const float*)d_in[22];
  const float* at_wmu  = (const float*)d_in[23];
  const float* at_wls  = (const float*)d_in[24];
  const float* at_bmu  = (const float*)d_in[25];
  const float* at_bls  = (const float*)d_in[26];
  const float* em_w    = (const float*)d_in[27];
  const float* em_b    = (const float*)d_in[28];
  const float* es_w    = (const float*)d_in[29];
  const float* es_b    = (const float*)d_in[30];
  const float* tm_w    = (const float*)d_in[31];
  const float* tm_b    = (const float*)d_in[32];
  const float* ts_w    = (const float*)d_in[33];
  const float* ts_b    = (const float*)d_in[34];

  float* ws = (float*)d_ws;
  const size_t SZ = (size_t)BL * ND;             // 8388608 floats (32 MB)
  float* X    = ws;                              // current activations
  float* INPX = ws + 1 * SZ;                     // x + pos_enc (cross-attn K/V)
  float* T1   = ws + 2 * SZ;                     // temp (attn out / ffn out)
  float* VB   = ws + 3 * SZ;
  float* QB   = ws + 4 * SZ;
  float* KB   = ws + 5 * SZ;
  float* H1   = QB;                              // ffn hidden overlaps QB+KB (2*SZ)
  float* WW   = ws + 6 * SZ;                     // sampled weight scratch (<=32768)
  float* WB   = WW + 32768;                      // sampled bias scratch (<=256)
  float* AWS  = INPX;                            // final-stage sampled alpha_w (INPX free)
  float* ABS  = AWS + 5 * NT * ND;               // +1310720
  float* ATWS = ABS + 5 * NT;                    // +10240
  float* ATBS = ATWS + 5 * ND;                   // +640 (len 5)

  // fold_in(key(42), c) for c = 0..45 (host-side, deterministic)
  uint32_t fk0[46], fk1[46];
  for (uint32_t c = 0; c < 46; ++c) tf2x32(0u, 42u, 0u, c, fk0[c], fk1[c]);

  auto sample = [&](const float* mu, const float* ls, float* outp, int n, int c) {
    sample_kernel<<<dim3((n + 255) / 256), dim3(256), 0, stream>>>(
        mu, ls, outp, n, fk0[c], fk1[c]);
  };
  auto gemm = [&](const float* A, int lda, const float* W, const float* bias,
                  float* C, int M, int N, int K, int act) {
    gemm_nt<<<dim3(N / 64, M / 64), dim3(256), 0, stream>>>(
        A, lda, W, bias, C, M, N, K, act);
  };

  embed_pe_kernel<<<dim3((BL * ND) / 256), dim3(256), 0, stream>>>(
      ev, mask, emb, X, INPX);

  int c = 0;
  for (int l = 0; l < 2; ++l) {
    for (int m = 0; m < 2; ++m) {              // m=0 self-attn, m=1 cross-attn
      const float* kvsrc = (m == 0) ? X : INPX;
      const int wb = l * 8 + m * 4;
      // Q projection (keys c, c+1)
      sample(dec_wmu + (size_t)wb * 16384, dec_wls + (size_t)wb * 16384, WW, 16384, c + 0);
      sample(dec_bmu + (size_t)wb * 128,   dec_bls + (size_t)wb * 128,   WB, 128,   c + 1);
      gemm(X, ND, WW, WB, QB, BL, ND, ND, 0);
      // K projection
      sample(dec_wmu + (size_t)(wb + 1) * 16384, dec_wls + (size_t)(wb + 1) * 16384, WW, 16384, c + 2);
      sample(dec_bmu + (size_t)(wb + 1) * 128,   dec_bls + (size_t)(wb + 1) * 128,   WB, 128,   c + 3);
      gemm(kvsrc, ND, WW, WB, KB, BL, ND, ND, 0);
      // V projection
      sample(dec_wmu + (size_t)(wb + 2) * 16384, dec_wls + (size_t)(wb + 2) * 16384, WW, 16384, c + 4);
      sample(dec_bmu + (size_t)(wb + 2) * 128,   dec_bls + (size_t)(wb + 2) * 128,   WB, 128,   c + 5);
      gemm(kvsrc, ND, WW, WB, VB, BL, ND, ND, 0);
      // attention -> T1
      attn_kernel<<<dim3(NB * NH), dim3(256), 0, stream>>>(QB, KB, VB, T1);
      // output projection -> KB (free after attention)
      sample(dec_wmu + (size_t)(wb + 3) * 16384, dec_wls + (size_t)(wb + 3) * 16384, WW, 16384, c + 6);
      sample(dec_bmu + (size_t)(wb + 3) * 128,   dec_bls + (size_t)(wb + 3) * 128,   WB, 128,   c + 7);
      gemm(T1, ND, WW, WB, KB, BL, ND, ND, 0);
      // x = LN(x + attn)
      add_ln_kernel<<<dim3(BL), dim3(128), 0, stream>>>(
          X, KB, ln_g + (size_t)(l * 3 + m) * ND, ln_b + (size_t)(l * 3 + m) * ND);
      c += 8;
    }
    // FFN
    sample(f1_wmu + (size_t)l * 32768, f1_wls + (size_t)l * 32768, WW, 32768, c + 0);
    sample(f1_bmu + (size_t)l * 256,   f1_bls + (size_t)l * 256,   WB, 256,   c + 1);
    gemm(X, ND, WW, WB, H1, BL, NDFF, ND, 1);                  // relu
    sample(f2_wmu + (size_t)l * 32768, f2_wls + (size_t)l * 32768, WW, 32768, c + 2);
    sample(f2_bmu + (size_t)l * 128,   f2_bls + (size_t)l * 128,   WB, 128,   c + 3);
    gemm(H1, NDFF, WW, WB, T1, BL, ND, NDFF, 0);
    add_ln_kernel<<<dim3(BL), dim3(128), 0, stream>>>(
        X, T1, ln_g + (size_t)(l * 3 + 2) * ND, ln_b + (size_t)(l * 3 + 2) * ND);
    c += 4;
  }

  // ---- final heads (c == 40) ----
  sample(a_wmu,  a_wls,  AWS,  5 * NT * ND, 40);
  sample(a_bmu,  a_bls,  ABS,  5 * NT,      41);
  sample(at_wmu, at_wls, ATWS, 5 * ND,      42);
  sample(at_bmu, at_bls, ATBS, 5,           43);

  // h = x[:, 0, :] -> strided A (lda = L*D). Logits/means/std-logits GEMMs.
  gemm(X, NL * ND, AWS,  ABS,  QB, NB, 5 * NT, ND, 0);   // alpha logits
  gemm(X, NL * ND, em_w, em_b, KB, NB, 5 * NT, ND, 0);   // means
  gemm(X, NL * ND, es_w, es_b, VB, NB, 5 * NT, ND, 0);   // std logits

  float* out = (float*)d_out;
  event_head_kernel<<<dim3((NB * NT) / 256), dim3(256), 0, stream>>>(
      QB, KB, VB, out, fk0[44], fk1[44]);
  time_head_kernel<<<dim3(NB / 256), dim3(256), 0, stream>>>(
      X, ATWS, ATBS, tm_w, tm_b, ts_w, ts_b, out + (size_t)NB * NT, fk0[45], fk1[45]);
}

// Round 2
// 1243.521 us; speedup vs baseline: 1.3682x; 1.3682x over previous
//
#include <hip/hip_runtime.h>
#include <cstdint>
#include <cstddef>

// ---------------------------------------------------------------------------
// HierarchicalNetwork: 2-layer Bayesian transformer decoder + mixture heads.
// B=512 L=128 D=128 H=4 dk=32 DFF=256 T=2048
// RNG: JAX threefry2x32 partitionable, fold_in(key(42), c) c=0..45 (verified R1).
// R2: MFMA bf16 attention (dk=32 == one 16x16x32 K-step), fused sampling
// kernel (46 launches -> 1), wave-per-row time head.
// ---------------------------------------------------------------------------

#define NB   512
#define NL   128
#define ND   128
#define NH   4
#define NDFF 256
#define NT   2048
#define BL   (NB * NL)          // 65536 rows

typedef __attribute__((ext_vector_type(8))) short bf16x8;   // 8 bf16 in 4 VGPR
typedef __attribute__((ext_vector_type(4))) float f32x4;

// ----------------------------- threefry2x32 --------------------------------
__host__ __device__ __forceinline__ void tf2x32(uint32_t k0, uint32_t k1,
                                                uint32_t x0, uint32_t x1,
                                                uint32_t& o0, uint32_t& o1)
{
  const uint32_t ks2 = k0 ^ k1 ^ 0x1BD11BDAu;
  x0 += k0; x1 += k1;
#define TF_RND(r) { x0 += x1; x1 = (x1 << (r)) | (x1 >> (32 - (r))); x1 ^= x0; }
  TF_RND(13) TF_RND(15) TF_RND(26) TF_RND(6)
  x0 += k1;  x1 += ks2 + 1u;
  TF_RND(17) TF_RND(29) TF_RND(16) TF_RND(24)
  x0 += ks2; x1 += k0 + 2u;
  TF_RND(13) TF_RND(15) TF_RND(26) TF_RND(6)
  x0 += k0;  x1 += k1 + 3u;
  TF_RND(17) TF_RND(29) TF_RND(16) TF_RND(24)
  x0 += k1;  x1 += ks2 + 4u;
  TF_RND(13) TF_RND(15) TF_RND(26) TF_RND(6)
  x0 += ks2; x1 += k0 + 5u;
#undef TF_RND
  o0 = x0; o1 = x1;
}

// XLA f32 erfinv (Giles). _rn ops keep XLA's separate roundings (no contract).
__device__ __forceinline__ float erfinv32(float x)
{
  float w = -log1pf(-__fmul_rn(x, x));
  float p;
  if (w < 5.0f) {
    w = w - 2.5f;
    p = 2.81022636e-08f;
    p = __fadd_rn( 3.43273939e-07f, __fmul_rn(p, w));
    p = __fadd_rn(-3.5233877e-06f,  __fmul_rn(p, w));
    p = __fadd_rn(-4.39150654e-06f, __fmul_rn(p, w));
    p = __fadd_rn( 0.00021858087f,  __fmul_rn(p, w));
    p = __fadd_rn(-0.00125372503f,  __fmul_rn(p, w));
    p = __fadd_rn(-0.00417768164f,  __fmul_rn(p, w));
    p = __fadd_rn( 0.246640727f,    __fmul_rn(p, w));
    p = __fadd_rn( 1.50140941f,     __fmul_rn(p, w));
  } else {
    w = sqrtf(w) - 3.0f;
    p = -0.000200214257f;
    p = __fadd_rn( 0.000100950558f, __fmul_rn(p, w));
    p = __fadd_rn( 0.00134934322f,  __fmul_rn(p, w));
    p = __fadd_rn(-0.00367342844f,  __fmul_rn(p, w));
    p = __fadd_rn( 0.00573950773f,  __fmul_rn(p, w));
    p = __fadd_rn(-0.0076224613f,   __fmul_rn(p, w));
    p = __fadd_rn( 0.00943887047f,  __fmul_rn(p, w));
    p = __fadd_rn( 1.00167406f,     __fmul_rn(p, w));
    p = __fadd_rn( 2.83297682f,     __fmul_rn(p, w));
  }
  return __fmul_rn(p, x);
}

__device__ __forceinline__ float bits_to_normal(uint32_t bits)
{
  const float lo = -0.99999994f;                 // nextafter(-1, 0)
  float f = __uint_as_float((bits >> 9) | 0x3F800000u) - 1.0f;
  float u = __fadd_rn(__fmul_rn(f, 2.0f), lo);
  u = fmaxf(lo, u);
  return __fmul_rn(1.41421356f, erfinv32(u));
}

// partitionable random_bits: bits[i] = o0^o1 of threefry(key, (0, i))
__device__ __forceinline__ float jax_normal_idx(uint32_t k0, uint32_t k1, uint32_t idx)
{
  uint32_t o0, o1;
  tf2x32(k0, k1, 0u, idx, o0, o1);
  return bits_to_normal(o0 ^ o1);
}

// RNE float->bf16 bits
__device__ __forceinline__ ushort f2bf(float f)
{
  uint32_t u = __float_as_uint(f);
  u += 0x7fffu + ((u >> 16) & 1u);
  return (ushort)(u >> 16);
}

// --------------------- fused Bayesian weight sampling ----------------------
// wall[] layout (floats): dec_w 16x16384 | dec_b 16x128 | f1w 2x32768 |
// f1b 2x256 | f2w 2x32768 | f2b 2x128 | alpha_w 5*T*D | alpha_b 5*T |
// at_w 5*D | at_b 5
#define SA_DECW 0
#define SA_DECB 262144
#define SA_F1W  264192
#define SA_F1B  329728
#define SA_F2W  330240
#define SA_F2B  395776
#define SA_AW   396032
#define SA_AB   1706752
#define SA_ATW  1716992
#define SA_ATB  1717632
#define SA_TOT  1717637

__global__ __launch_bounds__(256) void sample_all_kernel(
    const float* __restrict__ dec_wmu, const float* __restrict__ dec_wls,
    const float* __restrict__ dec_bmu, const float* __restrict__ dec_bls,
    const float* __restrict__ f1_wmu,  const float* __restrict__ f1_wls,
    const float* __restrict__ f1_bmu,  const float* __restrict__ f1_bls,
    const float* __restrict__ f2_wmu,  const float* __restrict__ f2_wls,
    const float* __restrict__ f2_bmu,  const float* __restrict__ f2_bls,
    const float* __restrict__ a_wmu,   const float* __restrict__ a_wls,
    const float* __restrict__ a_bmu,   const float* __restrict__ a_bls,
    const float* __restrict__ at_wmu,  const float* __restrict__ at_wls,
    const float* __restrict__ at_bmu,  const float* __restrict__ at_bls,
    float* __restrict__ wall)
{
  const int i = blockIdx.x * 256 + threadIdx.x;
  if (i >= SA_TOT) return;
  const float* mu; const float* ls;
  uint32_t c, idx;
  if (i < SA_DECB) {            // dec weights, seg s: key 2s (+4 if s>=8)
    int s = i >> 14;
    mu = dec_wmu + i; ls = dec_wls + i;
    c = 2u * s + (s >= 8 ? 4u : 0u); idx = (uint32_t)(i & 16383);
  } else if (i < SA_F1W) {      // dec biases
    int t = i - SA_DECB; int s = t >> 7;
    mu = dec_bmu + t; ls = dec_bls + t;
    c = 2u * s + 1u + (s >= 8 ? 4u : 0u); idx = (uint32_t)(t & 127);
  } else if (i < SA_F1B) {
    int t = i - SA_F1W; int s = t >> 15;
    mu = f1_wmu + t; ls = f1_wls + t;
    c = 16u + 20u * s; idx = (uint32_t)(t & 32767);
  } else if (i < SA_F2W) {
    int t = i - SA_F1B; int s = t >> 8;
    mu = f1_bmu + t; ls = f1_bls + t;
    c = 17u + 20u * s; idx = (uint32_t)(t & 255);
  } else if (i < SA_F2B) {
    int t = i - SA_F2W; int s = t >> 15;
    mu = f2_wmu + t; ls = f2_wls + t;
    c = 18u + 20u * s; idx = (uint32_t)(t & 32767);
  } else if (i < SA_AW) {
    int t = i - SA_F2B; int s = t >> 7;
    mu = f2_bmu + t; ls = f2_bls + t;
    c = 19u + 20u * s; idx = (uint32_t)(t & 127);
  } else if (i < SA_AB) {
    int t = i - SA_AW;
    mu = a_wmu + t; ls = a_wls + t; c = 40u; idx = (uint32_t)t;
  } else if (i < SA_ATW) {
    int t = i - SA_AB;
    mu = a_bmu + t; ls = a_bls + t; c = 41u; idx = (uint32_t)t;
  } else if (i < SA_ATB) {
    int t = i - SA_ATW;
    mu = at_wmu + t; ls = at_wls + t; c = 42u; idx = (uint32_t)t;
  } else {
    int t = i - SA_ATB;
    mu = at_bmu + t; ls = at_bls + t; c = 43u; idx = (uint32_t)t;
  }
  uint32_t k0, k1;
  tf2x32(0u, 42u, 0u, c, k0, k1);
  wall[i] = mu[0] + expf(ls[0]) * jax_normal_idx(k0, k1, idx);
}

// --------------------------- embedding + pos-enc ---------------------------
__global__ __launch_bounds__(256) void embed_pe_kernel(
    const int* __restrict__ ev, const int* __restrict__ mask,
    const float* __restrict__ emb, float* __restrict__ X, float* __restrict__ INPX)
{
  int i = blockIdx.x * 256 + threadIdx.x;
  if (i >= BL * ND) return;
  int d  = i & (ND - 1);
  int bl = i >> 7;
  int e  = ev[bl];
  int mk = mask[bl];
  float x   = emb[(size_t)e * ND + d];
  float div = expf((float)d * (float)(-9.210340371976184 / 128.0));
  float ang = (float)mk * div;
  float pe  = ((mk & 1) == 0) ? sinf(ang) : cosf(ang);
  X[i]    = x;
  INPX[i] = x + pe;
}

// ------------------------------- GEMM (NT) ---------------------------------
__global__ __launch_bounds__(256) void gemm_nt(
    const float* __restrict__ A, int lda,
    const float* __restrict__ W, const float* __restrict__ bias,
    float* __restrict__ C, int M, int N, int K, int act)
{
  __shared__ float As[16][64];
  __shared__ float Ws[16][64];
  const int tid = threadIdx.x;
  const int bm = blockIdx.y * 64;
  const int bn = blockIdx.x * 64;
  const int tr = tid >> 4, tc = tid & 15;
  const int lr = tid >> 2, lc = (tid & 3) << 2;
  float acc[4][4] = {{0.f}};

  for (int k0 = 0; k0 < K; k0 += 16) {
    float4 av = *(const float4*)(A + (size_t)(bm + lr) * lda + k0 + lc);
    float4 wv = *(const float4*)(W + (size_t)(bn + lr) * K   + k0 + lc);
    As[lc + 0][lr] = av.x; As[lc + 1][lr] = av.y;
    As[lc + 2][lr] = av.z; As[lc + 3][lr] = av.w;
    Ws[lc + 0][lr] = wv.x; Ws[lc + 1][lr] = wv.y;
    Ws[lc + 2][lr] = wv.z; Ws[lc + 3][lr] = wv.w;
    __syncthreads();
#pragma unroll
    for (int kk = 0; kk < 16; ++kk) {
      float a[4], w[4];
#pragma unroll
      for (int i = 0; i < 4; ++i) a[i] = As[kk][(tr << 2) + i];
#pragma unroll
      for (int j = 0; j < 4; ++j) w[j] = Ws[kk][(tc << 2) + j];
#pragma unroll
      for (int i = 0; i < 4; ++i)
#pragma unroll
        for (int j = 0; j < 4; ++j)
          acc[i][j] = fmaf(a[i], w[j], acc[i][j]);
    }
    __syncthreads();
  }

#pragma unroll
  for (int i = 0; i < 4; ++i) {
    int row = bm + (tr << 2) + i;
    int col = bn + (tc << 2);
    float4 o;
    o.x = acc[i][0] + bias[col + 0];
    o.y = acc[i][1] + bias[col + 1];
    o.z = acc[i][2] + bias[col + 2];
    o.w = acc[i][3] + bias[col + 3];
    if (act == 1) {
      o.x = fmaxf(o.x, 0.f); o.y = fmaxf(o.y, 0.f);
      o.z = fmaxf(o.z, 0.f); o.w = fmaxf(o.w, 0.f);
    }
    *(float4*)(C + (size_t)row * N + col) = o;
  }
}

// --------------------------- MFMA attention --------------------------------
// One block (4 waves) per (b,head). dk=32 = one 16x16x32 bf16 K-step.
// Wave w owns S/O rows [32w, 32w+32). Full-row softmax in registers
// (D-frag row = 4*(lane>>4)+reg), P round-trips LDS as bf16 A-fragments.
// V stored transposed (Vt[d][k]) so PV B-frags are contiguous ds_read_b128.
#define KPAD 40     // K rows padded to 40 bf16 (80 B, 16B-aligned)
#define VTPAD 136   // Vt rows padded to 136 bf16 (272 B)
#define PPAD 136

__global__ __launch_bounds__(256) void attn_mfma_kernel(
    const float* __restrict__ Qb, const float* __restrict__ Kb,
    const float* __restrict__ Vb, float* __restrict__ O)
{
  __shared__ ushort Kl[128][KPAD];
  __shared__ ushort Vt[32][VTPAD];
  __shared__ ushort Pl[128][PPAD];

  const int bh = blockIdx.x;
  const int b = bh >> 2, hh = bh & 3;
  const size_t base = (size_t)b * (NL * ND) + hh * 32;
  const int tid = threadIdx.x;

  // stage K -> Kl (bf16), V -> Vt (bf16 transposed)
  {
    const int q  = tid & 7;         // 4-float column block
    const int r0 = tid >> 3;        // row 0..31
#pragma unroll
    for (int rr = 0; rr < 4; ++rr) {
      const int row = r0 + 32 * rr;
      const float4 kv = *(const float4*)(Kb + base + (size_t)row * ND + q * 4);
      const float4 vv = *(const float4*)(Vb + base + (size_t)row * ND + q * 4);
      Kl[row][q * 4 + 0] = f2bf(kv.x); Kl[row][q * 4 + 1] = f2bf(kv.y);
      Kl[row][q * 4 + 2] = f2bf(kv.z); Kl[row][q * 4 + 3] = f2bf(kv.w);
      Vt[q * 4 + 0][row] = f2bf(vv.x); Vt[q * 4 + 1][row] = f2bf(vv.y);
      Vt[q * 4 + 2][row] = f2bf(vv.z); Vt[q * 4 + 3][row] = f2bf(vv.w);
    }
  }
  __syncthreads();

  const int w   = tid >> 6;
  const int l   = tid & 63;
  const int g   = l >> 4;          // k-group 0..3
  const int r16 = l & 15;

  // ---- phase 1: S = (1/sqrt(dk)) * Q K^T, rows [32w,32w+32) ----
  bf16x8 qa[2];
#pragma unroll
  for (int t = 0; t < 2; ++t) {
    const int row = 32 * w + 16 * t + r16;
    const float* qp = Qb + base + (size_t)row * ND + 8 * g;
    const float4 q0 = *(const float4*)qp;
    const float4 q1 = *(const float4*)(qp + 4);
    bf16x8 v;
    v[0] = f2bf(q0.x); v[1] = f2bf(q0.y); v[2] = f2bf(q0.z); v[3] = f2bf(q0.w);
    v[4] = f2bf(q1.x); v[5] = f2bf(q1.y); v[6] = f2bf(q1.z); v[7] = f2bf(q1.w);
    qa[t] = v;
  }
  bf16x8 kbf[8];
#pragma unroll
  for (int c = 0; c < 8; ++c)
    kbf[c] = *(const bf16x8*)&Kl[16 * c + r16][8 * g];

  const f32x4 zero = {0.f, 0.f, 0.f, 0.f};
  f32x4 sacc[2][8];
#pragma unroll
  for (int t = 0; t < 2; ++t)
#pragma unroll
    for (int c = 0; c < 8; ++c)
      sacc[t][c] = __builtin_amdgcn_mfma_f32_16x16x32_bf16(qa[t], kbf[c], zero, 0, 0, 0);

  // ---- phase 2: row softmax (row = 32w+16t+4g+r), write P (bf16) ----
  const float scale = 0.1767766952966369f;       // 1/sqrt(32)
#pragma unroll
  for (int t = 0; t < 2; ++t) {
#pragma unroll
    for (int r = 0; r < 4; ++r) {
      float s[8];
      float m = -1e30f;
#pragma unroll
      for (int c = 0; c < 8; ++c) { s[c] = sacc[t][c][r] * scale; m = fmaxf(m, s[c]); }
#pragma unroll
      for (int o = 1; o < 16; o <<= 1) m = fmaxf(m, __shfl_xor(m, o));
      float sum = 0.f;
#pragma unroll
      for (int c = 0; c < 8; ++c) { s[c] = __expf(s[c] - m); sum += s[c]; }
#pragma unroll
      for (int o = 1; o < 16; o <<= 1) sum += __shfl_xor(sum, o);
      const float inv = 1.0f / sum;
      const int row = 32 * w + 16 * t + 4 * g + r;
#pragma unroll
      for (int c = 0; c < 8; ++c)
        Pl[row][16 * c + r16] = f2bf(s[c] * inv);
    }
  }
  __syncthreads();

  // ---- phase 3: O = P V  (K=128 -> 4 k-steps) ----
  f32x4 oacc[2][2] = {{zero, zero}, {zero, zero}};
#pragma unroll
  for (int ks = 0; ks < 4; ++ks) {
    bf16x8 pa[2], vbf[2];
#pragma unroll
    for (int t = 0; t < 2; ++t)
      pa[t] = *(const bf16x8*)&Pl[32 * w + 16 * t + r16][32 * ks + 8 * g];
#pragma unroll
    for (int cc = 0; cc < 2; ++cc)
      vbf[cc] = *(const bf16x8*)&Vt[16 * cc + r16][32 * ks + 8 * g];
#pragma unroll
    for (int t = 0; t < 2; ++t)
#pragma unroll
      for (int cc = 0; cc < 2; ++cc)
        oacc[t][cc] = __builtin_amdgcn_mfma_f32_16x16x32_bf16(pa[t], vbf[cc], oacc[t][cc], 0, 0, 0);
  }

  // ---- store O (fp32, same (B,L,D) layout) ----
#pragma unroll
  for (int t = 0; t < 2; ++t)
#pragma unroll
    for (int cc = 0; cc < 2; ++cc)
#pragma unroll
      for (int r = 0; r < 4; ++r) {
        const int row = 32 * w + 16 * t + 4 * g + r;
        const int col = 16 * cc + r16;
        O[base + (size_t)row * ND + col] = oacc[t][cc][r];
      }
}

// -------------------------- residual + layernorm ---------------------------
__global__ __launch_bounds__(128) void add_ln_kernel(
    float* __restrict__ x, const float* __restrict__ a,
    const float* __restrict__ g, const float* __restrict__ bb)
{
  const int row = blockIdx.x;
  const int t = threadIdx.x;
  const size_t off = (size_t)row * ND + t;
  float v = x[off] + a[off];
  float s = v;
#pragma unroll
  for (int o = 32; o; o >>= 1) s += __shfl_xor(s, o);
  __shared__ float red[4];
  if ((t & 63) == 0) red[t >> 6] = s;
  __syncthreads();
  float mean = (red[0] + red[1]) * (1.0f / 128.0f);
  float d = v - mean;
  float q = d * d;
#pragma unroll
  for (int o = 32; o; o >>= 1) q += __shfl_xor(q, o);
  if ((t & 63) == 0) red[2 + (t >> 6)] = q;
  __syncthreads();
  float var = (red[2] + red[3]) * (1.0f / 128.0f);
  x[off] = d / sqrtf(var + 1e-5f) * g[t] + bb[t];
}

// ------------------------------ event head ---------------------------------
__global__ __launch_bounds__(256) void event_head_kernel(
    const float* __restrict__ LA, const float* __restrict__ MB,
    const float* __restrict__ SB, float* __restrict__ out,
    uint32_t k0, uint32_t k1)
{
  int i = blockIdx.x * 256 + threadIdx.x;        // over B*T
  if (i >= NB * NT) return;
  int b = i >> 11, t = i & (NT - 1);
  size_t base = (size_t)b * (5 * NT) + t;
  float lg[5];
  float mx = -1e30f;
#pragma unroll
  for (int k = 0; k < 5; ++k) { lg[k] = LA[base + (size_t)k * NT]; mx = fmaxf(mx, lg[k]); }
  float se = 0.f;
#pragma unroll
  for (int k = 0; k < 5; ++k) { lg[k] = expf(lg[k] - mx); se += lg[k]; }
  float inv = 1.0f / se;
  float acc = 0.f;
#pragma unroll
  for (int k = 0; k < 5; ++k) {
    float nz = jax_normal_idx(k0, k1, (uint32_t)((b * 5 + k) * NT + t));
    float mean = MB[base + (size_t)k * NT];
    float sd   = expf(SB[base + (size_t)k * NT]);
    acc += (lg[k] * inv) * (mean + sd * nz);
  }
  out[i] = acc;
}

// ------------------------------- time head ---------------------------------
// One wave per batch row: lanes split D=128 in two, shuffle-reduce 15 dots.
__global__ __launch_bounds__(64) void time_head_kernel(
    const float* __restrict__ X, const float* __restrict__ atw,
    const float* __restrict__ atb, const float* __restrict__ tmw,
    const float* __restrict__ tmb, const float* __restrict__ tsw,
    const float* __restrict__ tsb, float* __restrict__ out,
    uint32_t k0, uint32_t k1)
{
  const int b = blockIdx.x;
  const int l = threadIdx.x;
  const float* h = X + (size_t)b * (NL * ND);    // x[b, 0, :]
  const float h0 = h[l], h1 = h[l + 64];
  float lg[5], tm[5], tsl[5];
#pragma unroll
  for (int k = 0; k < 5; ++k) {
    float s0 = fmaf(h0, atw[k * ND + l], h1 * atw[k * ND + l + 64]);
    float s1 = fmaf(h0, tmw[k * ND + l], h1 * tmw[k * ND + l + 64]);
    float s2 = fmaf(h0, tsw[k * ND + l], h1 * tsw[k * ND + l + 64]);
#pragma unroll
    for (int o = 32; o; o >>= 1) {
      s0 += __shfl_xor(s0, o);
      s1 += __shfl_xor(s1, o);
      s2 += __shfl_xor(s2, o);
    }
    lg[k] = s0 + atb[k]; tm[k] = s1 + tmb[k]; tsl[k] = s2 + tsb[k];
  }
  if (l == 0) {
    float mx = lg[0];
    for (int k = 1; k < 5; ++k) mx = fmaxf(mx, lg[k]);
    float se = 0.f;
    for (int k = 0; k < 5; ++k) { lg[k] = expf(lg[k] - mx); se += lg[k]; }
    float acc = 0.f;
    for (int k = 0; k < 5; ++k) {
      float nz = jax_normal_idx(k0, k1, (uint32_t)(b * 5 + k));
      acc += (lg[k] / se) * (tm[k] + expf(tsl[k]) * nz);
    }
    out[b] = acc;
  }
}

// ------------------------------ host driver --------------------------------
extern "C" void kernel_launch(void* const* d_in, const int* in_sizes, int n_in,
                              void* d_out, int out_size, void* d_ws, size_t ws_size,
                              hipStream_t stream)
{
  (void)in_sizes; (void)n_in; (void)out_size; (void)ws_size;

  const int*   ev      = (const int*)d_in[0];
  const int*   mask    = (const int*)d_in[2];
  const float* emb     = (const float*)d_in[4];
  const float* dec_wmu = (const float*)d_in[5];
  const float* dec_wls = (const float*)d_in[6];
  const float* dec_bmu = (const float*)d_in[7];
  const float* dec_bls = (const float*)d_in[8];
  const float* f1_wmu  = (const float*)d_in[9];
  const float* f1_wls  = (const float*)d_in[10];
  const float* f1_bmu  = (const float*)d_in[11];
  const float* f1_bls  = (const float*)d_in[12];
  const float* f2_wmu  = (const float*)d_in[13];
  const float* f2_wls  = (const float*)d_in[14];
  const float* f2_bmu  = (const float*)d_in[15];
  const float* f2_bls  = (const float*)d_in[16];
  const float* ln_g    = (const float*)d_in[17];
  const float* ln_b    = (const float*)d_in[18];
  const float* a_wmu   = (const float*)d_in[19];
  const float* a_wls   = (const float*)d_in[20];
  const float* a_bmu   = (const float*)d_in[21];
  const float* a_bls   = (const float*)d_in[22];
  const float* at_wmu  = (const float*)d_in[23];
  const float* at_wls  = (const float*)d_in[24];
  const float* at_bmu  = (const float*)d_in[25];
  const float* at_bls  = (const float*)d_in[26];
  const float* em_w    = (const float*)d_in[27];
  const float* em_b    = (const float*)d_in[28];
  const float* es_w    = (const float*)d_in[29];
  const float* es_b    = (const float*)d_in[30];
  const float* tm_w    = (const float*)d_in[31];
  const float* tm_b    = (const float*)d_in[32];
  const float* ts_w    = (const float*)d_in[33];
  const float* ts_b    = (const float*)d_in[34];

  float* ws = (float*)d_ws;
  const size_t SZ = (size_t)BL * ND;             // 8388608 floats (32 MB)
  float* X    = ws;
  float* INPX = ws + 1 * SZ;
  float* T1   = ws + 2 * SZ;
  float* VB   = ws + 3 * SZ;
  float* QB   = ws + 4 * SZ;
  float* KB   = ws + 5 * SZ;
  float* H1   = QB;                              // ffn hidden reuses QB+KB
  float* WALL = ws + 6 * SZ;                     // all sampled weights (6.9 MB)

  // fold_in(key(42), c) for noise heads (44,45)
  uint32_t fk0[46], fk1[46];
  for (uint32_t c = 0; c < 46; ++c) tf2x32(0u, 42u, 0u, c, fk0[c], fk1[c]);

  auto gemm = [&](const float* A, int lda, const float* W, const float* bias,
                  float* C, int M, int N, int K, int act) {
    gemm_nt<<<dim3(N / 64, M / 64), dim3(256), 0, stream>>>(
        A, lda, W, bias, C, M, N, K, act);
  };

  sample_all_kernel<<<dim3((SA_TOT + 255) / 256), dim3(256), 0, stream>>>(
      dec_wmu, dec_wls, dec_bmu, dec_bls,
      f1_wmu, f1_wls, f1_bmu, f1_bls,
      f2_wmu, f2_wls, f2_bmu, f2_bls,
      a_wmu, a_wls, a_bmu, a_bls,
      at_wmu, at_wls, at_bmu, at_bls, WALL);

  embed_pe_kernel<<<dim3((BL * ND) / 256), dim3(256), 0, stream>>>(
      ev, mask, emb, X, INPX);

  for (int l = 0; l < 2; ++l) {
    for (int m = 0; m < 2; ++m) {              // m=0 self-attn, m=1 cross-attn
      const float* kvsrc = (m == 0) ? X : INPX;
      const int s0 = l * 8 + m * 4;            // dec segment base
      const float* Wq = WALL + SA_DECW + (size_t)(s0 + 0) * 16384;
      const float* Wk = WALL + SA_DECW + (size_t)(s0 + 1) * 16384;
      const float* Wv = WALL + SA_DECW + (size_t)(s0 + 2) * 16384;
      const float* Wo = WALL + SA_DECW + (size_t)(s0 + 3) * 16384;
      const float* Bq = WALL + SA_DECB + (size_t)(s0 + 0) * 128;
      const float* Bk = WALL + SA_DECB + (size_t)(s0 + 1) * 128;
      const float* Bv = WALL + SA_DECB + (size_t)(s0 + 2) * 128;
      const float* Bo = WALL + SA_DECB + (size_t)(s0 + 3) * 128;
      gemm(X,     ND, Wq, Bq, QB, BL, ND, ND, 0);
      gemm(kvsrc, ND, Wk, Bk, KB, BL, ND, ND, 0);
      gemm(kvsrc, ND, Wv, Bv, VB, BL, ND, ND, 0);
      attn_mfma_kernel<<<dim3(NB * NH), dim3(256), 0, stream>>>(QB, KB, VB, T1);
      gemm(T1, ND, Wo, Bo, KB, BL, ND, ND, 0);
      add_ln_kernel<<<dim3(BL), dim3(128), 0, stream>>>(
          X, KB, ln_g + (size_t)(l * 3 + m) * ND, ln_b + (size_t)(l * 3 + m) * ND);
    }
    // FFN
    gemm(X, ND, WALL + SA_F1W + (size_t)l * 32768, WALL + SA_F1B + (size_t)l * 256,
         H1, BL, NDFF, ND, 1);
    gemm(H1, NDFF, WALL + SA_F2W + (size_t)l * 32768, WALL + SA_F2B + (size_t)l * 128,
         T1, BL, ND, NDFF, 0);
    add_ln_kernel<<<dim3(BL), dim3(128), 0, stream>>>(
        X, T1, ln_g + (size_t)(l * 3 + 2) * ND, ln_b + (size_t)(l * 3 + 2) * ND);
  }

  // ---- final heads ----
  gemm(X, NL * ND, WALL + SA_AW, WALL + SA_AB, QB, NB, 5 * NT, ND, 0);  // alpha logits
  gemm(X, NL * ND, em_w, em_b, KB, NB, 5 * NT, ND, 0);                  // means
  gemm(X, NL * ND, es_w, es_b, VB, NB, 5 * NT, ND, 0);                  // std logits

  float* out = (float*)d_out;
  event_head_kernel<<<dim3((NB * NT) / 256), dim3(256), 0, stream>>>(
      QB, KB, VB, out, fk0[44], fk1[44]);
  time_head_kernel<<<dim3(NB), dim3(64), 0, stream>>>(
      X, WALL + SA_ATW, WALL + SA_ATB, tm_w, tm_b, ts_w, ts_b,
      out + (size_t)NB * NT, fk0[45], fk1[45]);
}

// Round 3
// 486.492 us; speedup vs baseline: 3.4973x; 2.5561x over previous
//
#include <hip/hip_runtime.h>
#include <cstdint>
#include <cstddef>

// ---------------------------------------------------------------------------
// HierarchicalNetwork: 2-layer Bayesian transformer decoder + mixture heads.
// B=512 L=128 D=128 H=4 dk=32 DFF=256 T=2048
// RNG: JAX threefry2x32 partitionable, fold_in(key(42), c) c=0..45 (verified).
// R3: all GEMMs -> bf16 MFMA (tile 128x128, W in LDS, LDS-routed C stores),
// fused residual+LN epilogue (kills 6 add_ln passes), bf16 activations
// (fp32 master X kept for LN/residual exactness), bf16 attention I/O.
// ---------------------------------------------------------------------------

#define NB   512
#define NL   128
#define ND   128
#define NH   4
#define NDFF 256
#define NT   2048
#define BL   (NB * NL)          // 65536 rows

typedef __attribute__((ext_vector_type(8))) short bf16x8;   // 8 bf16 in 4 VGPR
typedef __attribute__((ext_vector_type(4))) float f32x4;

// ----------------------------- threefry2x32 --------------------------------
__host__ __device__ __forceinline__ void tf2x32(uint32_t k0, uint32_t k1,
                                                uint32_t x0, uint32_t x1,
                                                uint32_t& o0, uint32_t& o1)
{
  const uint32_t ks2 = k0 ^ k1 ^ 0x1BD11BDAu;
  x0 += k0; x1 += k1;
#define TF_RND(r) { x0 += x1; x1 = (x1 << (r)) | (x1 >> (32 - (r))); x1 ^= x0; }
  TF_RND(13) TF_RND(15) TF_RND(26) TF_RND(6)
  x0 += k1;  x1 += ks2 + 1u;
  TF_RND(17) TF_RND(29) TF_RND(16) TF_RND(24)
  x0 += ks2; x1 += k0 + 2u;
  TF_RND(13) TF_RND(15) TF_RND(26) TF_RND(6)
  x0 += k0;  x1 += k1 + 3u;
  TF_RND(17) TF_RND(29) TF_RND(16) TF_RND(24)
  x0 += k1;  x1 += ks2 + 4u;
  TF_RND(13) TF_RND(15) TF_RND(26) TF_RND(6)
  x0 += ks2; x1 += k0 + 5u;
#undef TF_RND
  o0 = x0; o1 = x1;
}

// XLA f32 erfinv (Giles). _rn ops keep XLA's separate roundings (no contract).
__device__ __forceinline__ float erfinv32(float x)
{
  float w = -log1pf(-__fmul_rn(x, x));
  float p;
  if (w < 5.0f) {
    w = w - 2.5f;
    p = 2.81022636e-08f;
    p = __fadd_rn( 3.43273939e-07f, __fmul_rn(p, w));
    p = __fadd_rn(-3.5233877e-06f,  __fmul_rn(p, w));
    p = __fadd_rn(-4.39150654e-06f, __fmul_rn(p, w));
    p = __fadd_rn( 0.00021858087f,  __fmul_rn(p, w));
    p = __fadd_rn(-0.00125372503f,  __fmul_rn(p, w));
    p = __fadd_rn(-0.00417768164f,  __fmul_rn(p, w));
    p = __fadd_rn( 0.246640727f,    __fmul_rn(p, w));
    p = __fadd_rn( 1.50140941f,     __fmul_rn(p, w));
  } else {
    w = sqrtf(w) - 3.0f;
    p = -0.000200214257f;
    p = __fadd_rn( 0.000100950558f, __fmul_rn(p, w));
    p = __fadd_rn( 0.00134934322f,  __fmul_rn(p, w));
    p = __fadd_rn(-0.00367342844f,  __fmul_rn(p, w));
    p = __fadd_rn( 0.00573950773f,  __fmul_rn(p, w));
    p = __fadd_rn(-0.0076224613f,   __fmul_rn(p, w));
    p = __fadd_rn( 0.00943887047f,  __fmul_rn(p, w));
    p = __fadd_rn( 1.00167406f,     __fmul_rn(p, w));
    p = __fadd_rn( 2.83297682f,     __fmul_rn(p, w));
  }
  return __fmul_rn(p, x);
}

__device__ __forceinline__ float bits_to_normal(uint32_t bits)
{
  const float lo = -0.99999994f;                 // nextafter(-1, 0)
  float f = __uint_as_float((bits >> 9) | 0x3F800000u) - 1.0f;
  float u = __fadd_rn(__fmul_rn(f, 2.0f), lo);
  u = fmaxf(lo, u);
  return __fmul_rn(1.41421356f, erfinv32(u));
}

__device__ __forceinline__ float jax_normal_idx(uint32_t k0, uint32_t k1, uint32_t idx)
{
  uint32_t o0, o1;
  tf2x32(k0, k1, 0u, idx, o0, o1);
  return bits_to_normal(o0 ^ o1);
}

// RNE float->bf16 bits
__device__ __forceinline__ ushort f2bf(float f)
{
  uint32_t u = __float_as_uint(f);
  u += 0x7fffu + ((u >> 16) & 1u);
  return (ushort)(u >> 16);
}

// --------------------- fused Bayesian weight sampling ----------------------
// linear index space (verified R2); weights -> bf16 WBF, biases -> fp32 WF32
#define SA_DECB 262144
#define SA_F1W  264192
#define SA_F1B  329728
#define SA_F2W  330240
#define SA_F2B  395776
#define SA_AW   396032
#define SA_AB   1706752
#define SA_ATW  1716992
#define SA_ATB  1717632
#define SA_TOT  1717637

#define BW_DEC  0
#define BW_F1   262144
#define BW_F2   327680
#define BW_AW   393216
#define BW_TOT  1703936

#define BF_DECB 0
#define BF_F1B  2048
#define BF_F2B  2560
#define BF_AB   2816
#define BF_ATW  13056
#define BF_ATB  13696
#define BF_TOT  13701

__global__ __launch_bounds__(256) void sample_all_kernel(
    const float* __restrict__ dec_wmu, const float* __restrict__ dec_wls,
    const float* __restrict__ dec_bmu, const float* __restrict__ dec_bls,
    const float* __restrict__ f1_wmu,  const float* __restrict__ f1_wls,
    const float* __restrict__ f1_bmu,  const float* __restrict__ f1_bls,
    const float* __restrict__ f2_wmu,  const float* __restrict__ f2_wls,
    const float* __restrict__ f2_bmu,  const float* __restrict__ f2_bls,
    const float* __restrict__ a_wmu,   const float* __restrict__ a_wls,
    const float* __restrict__ a_bmu,   const float* __restrict__ a_bls,
    const float* __restrict__ at_wmu,  const float* __restrict__ at_wls,
    const float* __restrict__ at_bmu,  const float* __restrict__ at_bls,
    ushort* __restrict__ wbf, float* __restrict__ wf32)
{
  const int i = blockIdx.x * 256 + threadIdx.x;
  if (i >= SA_TOT) return;
  const float* mu; const float* ls;
  uint32_t c, idx;
  int bf_dst = -1;            // >=0: bf16 dest offset; else f32 dest offset
  int f32_dst = -1;
  if (i < SA_DECB) {
    int s = i >> 14;
    mu = dec_wmu + i; ls = dec_wls + i;
    c = 2u * s + (s >= 8 ? 4u : 0u); idx = (uint32_t)(i & 16383);
    bf_dst = BW_DEC + i;
  } else if (i < SA_F1W) {
    int t = i - SA_DECB; int s = t >> 7;
    mu = dec_bmu + t; ls = dec_bls + t;
    c = 2u * s + 1u + (s >= 8 ? 4u : 0u); idx = (uint32_t)(t & 127);
    f32_dst = BF_DECB + t;
  } else if (i < SA_F1B) {
    int t = i - SA_F1W; int s = t >> 15;
    mu = f1_wmu + t; ls = f1_wls + t;
    c = 16u + 20u * s; idx = (uint32_t)(t & 32767);
    bf_dst = BW_F1 + t;
  } else if (i < SA_F2W) {
    int t = i - SA_F1B; int s = t >> 8;
    mu = f1_bmu + t; ls = f1_bls + t;
    c = 17u + 20u * s; idx = (uint32_t)(t & 255);
    f32_dst = BF_F1B + t;
  } else if (i < SA_F2B) {
    int t = i - SA_F2W; int s = t >> 15;
    mu = f2_wmu + t; ls = f2_wls + t;
    c = 18u + 20u * s; idx = (uint32_t)(t & 32767);
    bf_dst = BW_F2 + t;
  } else if (i < SA_AW) {
    int t = i - SA_F2B; int s = t >> 7;
    mu = f2_bmu + t; ls = f2_bls + t;
    c = 19u + 20u * s; idx = (uint32_t)(t & 127);
    f32_dst = BF_F2B + t;
  } else if (i < SA_AB) {
    int t = i - SA_AW;
    mu = a_wmu + t; ls = a_wls + t; c = 40u; idx = (uint32_t)t;
    bf_dst = BW_AW + t;
  } else if (i < SA_ATW) {
    int t = i - SA_AB;
    mu = a_bmu + t; ls = a_bls + t; c = 41u; idx = (uint32_t)t;
    f32_dst = BF_AB + t;
  } else if (i < SA_ATB) {
    int t = i - SA_ATW;
    mu = at_wmu + t; ls = at_wls + t; c = 42u; idx = (uint32_t)t;
    f32_dst = BF_ATW + t;
  } else {
    int t = i - SA_ATB;
    mu = at_bmu + t; ls = at_bls + t; c = 43u; idx = (uint32_t)t;
    f32_dst = BF_ATB + t;
  }
  uint32_t k0, k1;
  tf2x32(0u, 42u, 0u, c, k0, k1);
  float v = mu[0] + expf(ls[0]) * jax_normal_idx(k0, k1, idx);
  if (bf_dst >= 0) wbf[bf_dst] = f2bf(v);
  else             wf32[f32_dst] = v;
}

// ------------------------- fp32 -> bf16 convert ----------------------------
__global__ __launch_bounds__(256) void conv_bf16_kernel(
    const float* __restrict__ src, ushort* __restrict__ dst, int n)
{
  int i = blockIdx.x * 256 + threadIdx.x;
  if (i < n) dst[i] = f2bf(src[i]);
}

// --------------------------- embedding + pos-enc ---------------------------
__global__ __launch_bounds__(256) void embed_pe_kernel(
    const int* __restrict__ ev, const int* __restrict__ mask,
    const float* __restrict__ emb, float* __restrict__ X,
    ushort* __restrict__ Xbf, ushort* __restrict__ INPXbf)
{
  int i = blockIdx.x * 256 + threadIdx.x;
  if (i >= BL * ND) return;
  int d  = i & (ND - 1);
  int bl = i >> 7;
  int e  = ev[bl];
  int mk = mask[bl];
  float x   = emb[(size_t)e * ND + d];
  float div = expf((float)d * (float)(-9.210340371976184 / 128.0));
  float ang = (float)mk * div;
  float pe  = ((mk & 1) == 0) ? sinf(ang) : cosf(ang);
  X[i]      = x;
  Xbf[i]    = f2bf(x);
  INPXbf[i] = f2bf(x + pe);
}

// --------------------------- bf16 MFMA GEMM --------------------------------
// C[M,N] = A[M,K] @ W[N,K]^T + bias.  Tile 128x128, grid (N/128, M/128),
// 4 waves, wave w owns rows [32w,32w+32).  W slice staged in LDS.
// MODE 0: fp32 C (LDS-routed coalesced store)
// MODE 1: bf16 C
// MODE 2: relu + bf16 C
// MODE 3: fused residual+LayerNorm -> fp32 X + bf16 Xbf (+optional Hb rows)
template <int KT, int MODE>
__global__ __launch_bounds__(256) void gemm_mfma(
    const ushort* __restrict__ A, int lda,
    const ushort* __restrict__ W, const float* __restrict__ bias,
    float* __restrict__ Cf, ushort* __restrict__ Cb,
    const float* __restrict__ resid,
    const float* __restrict__ lng, const float* __restrict__ lnb,
    ushort* __restrict__ Hb, int ldc)
{
  constexpr int WROW = KT + 8;                          // ushort stride
  constexpr size_t WBYTES = (size_t)128 * WROW * 2;
  constexpr size_t CBYTES = (MODE == 1 || MODE == 2) ? (size_t)128 * 136 * 2
                                                     : (size_t)128 * 132 * 4;
  constexpr size_t SBYTES = WBYTES > CBYTES ? WBYTES : CBYTES;
  __shared__ char smem[SBYTES];
  ushort (*Wl)[WROW] = (ushort(*)[WROW])smem;

  const int tid = threadIdx.x;
  const int bn = blockIdx.x * 128;
  const int bm = blockIdx.y * 128;
  const int w = tid >> 6, l = tid & 63;
  const int r16 = l & 15, g = l >> 4;

  // stage W rows [bn, bn+128) -> LDS (padded)
  {
    constexpr int CPR = KT / 8;
    for (int ci = tid; ci < 128 * CPR; ci += 256) {
      int row = ci / CPR, q = ci % CPR;
      *(bf16x8*)&Wl[row][q * 8] =
          *(const bf16x8*)(W + (size_t)(bn + row) * KT + q * 8);
    }
  }
  __syncthreads();

  f32x4 acc[2][8];
#pragma unroll
  for (int t = 0; t < 2; ++t)
#pragma unroll
    for (int c = 0; c < 8; ++c) acc[t][c] = f32x4{0.f, 0.f, 0.f, 0.f};

#pragma unroll
  for (int ks = 0; ks < KT / 32; ++ks) {
    bf16x8 a[2];
#pragma unroll
    for (int t = 0; t < 2; ++t)
      a[t] = *(const bf16x8*)(A + (size_t)(bm + 32 * w + 16 * t + r16) * lda
                              + 32 * ks + 8 * g);
    bf16x8 bfr[8];
#pragma unroll
    for (int c = 0; c < 8; ++c)
      bfr[c] = *(const bf16x8*)&Wl[16 * c + r16][32 * ks + 8 * g];
#pragma unroll
    for (int t = 0; t < 2; ++t)
#pragma unroll
      for (int c = 0; c < 8; ++c)
        acc[t][c] = __builtin_amdgcn_mfma_f32_16x16x32_bf16(a[t], bfr[c],
                                                            acc[t][c], 0, 0, 0);
  }

  float bcol[8];
#pragma unroll
  for (int c = 0; c < 8; ++c) bcol[c] = bias[bn + 16 * c + r16];

  __syncthreads();                       // Wl dead -> reuse as C tile

  if constexpr (MODE == 1 || MODE == 2) {
    ushort (*Cl)[136] = (ushort(*)[136])smem;
#pragma unroll
    for (int t = 0; t < 2; ++t)
#pragma unroll
      for (int c = 0; c < 8; ++c)
#pragma unroll
        for (int r = 0; r < 4; ++r) {
          float o = acc[t][c][r] + bcol[c];
          if (MODE == 2) o = fmaxf(o, 0.f);
          Cl[32 * w + 16 * t + 4 * g + r][16 * c + r16] = f2bf(o);
        }
    __syncthreads();
#pragma unroll
    for (int i = 0; i < 8; ++i) {
      int row = 32 * w + 4 * i + (l >> 4);
      int q = l & 15;
      bf16x8 v = *(const bf16x8*)&Cl[row][8 * q];
      *(bf16x8*)(Cb + (size_t)(bm + row) * ldc + bn + 8 * q) = v;
    }
  } else {
    float (*Cl)[132] = (float(*)[132])smem;
#pragma unroll
    for (int t = 0; t < 2; ++t)
#pragma unroll
      for (int c = 0; c < 8; ++c)
#pragma unroll
        for (int r = 0; r < 4; ++r)
          Cl[32 * w + 16 * t + 4 * g + r][16 * c + r16] = acc[t][c][r] + bcol[c];
    __syncthreads();
    if constexpr (MODE == 0) {
#pragma unroll
      for (int i = 0; i < 16; ++i) {
        int ci = l + 64 * i;
        int row = 32 * w + (ci >> 5), q = ci & 31;
        float4 v = *(const float4*)&Cl[row][4 * q];
        *(float4*)(Cf + (size_t)(bm + row) * ldc + bn + 4 * q) = v;
      }
    } else {                              // MODE 3: residual + LayerNorm
      const int half = l >> 5, c32 = l & 31;
      float4 g4 = *(const float4*)(lng + 4 * c32);
      float4 b4 = *(const float4*)(lnb + 4 * c32);
#pragma unroll
      for (int i = 0; i < 16; ++i) {
        int row = 32 * w + 2 * i + half;
        int grow = bm + row;
        float4 cv = *(const float4*)&Cl[row][4 * c32];
        float4 rv = *(const float4*)(resid + (size_t)grow * ldc + 4 * c32);
        float x0 = cv.x + rv.x, x1 = cv.y + rv.y;
        float x2 = cv.z + rv.z, x3 = cv.w + rv.w;
        float s = x0 + x1 + x2 + x3;
#pragma unroll
        for (int o = 1; o < 32; o <<= 1) s += __shfl_xor(s, o);
        float mean = s * (1.0f / 128.0f);
        float d0 = x0 - mean, d1 = x1 - mean, d2 = x2 - mean, d3 = x3 - mean;
        float q = d0 * d0 + d1 * d1 + d2 * d2 + d3 * d3;
#pragma unroll
        for (int o = 1; o < 32; o <<= 1) q += __shfl_xor(q, o);
        float inv = 1.0f / sqrtf(q * (1.0f / 128.0f) + 1e-5f);
        float o0 = d0 * inv * g4.x + b4.x;
        float o1 = d1 * inv * g4.y + b4.y;
        float o2 = d2 * inv * g4.z + b4.z;
        float o3 = d3 * inv * g4.w + b4.w;
        *(float4*)(Cf + (size_t)grow * ldc + 4 * c32) = float4{o0, o1, o2, o3};
        ushort4 hv; hv.x = f2bf(o0); hv.y = f2bf(o1); hv.z = f2bf(o2); hv.w = f2bf(o3);
        *(ushort4*)(Cb + (size_t)grow * ldc + 4 * c32) = hv;
        if (Hb && (grow & 127) == 0)
          *(ushort4*)(Hb + (size_t)(grow >> 7) * 128 + 4 * c32) = hv;
      }
    }
  }
}

// --------------------------- MFMA attention (bf16 I/O) ---------------------
#define KPAD 40
#define VTPAD 136
#define PPAD 136

__global__ __launch_bounds__(256) void attn_mfma_kernel(
    const ushort* __restrict__ Qb, const ushort* __restrict__ Kb,
    const ushort* __restrict__ Vb, ushort* __restrict__ O)
{
  __shared__ ushort Kl[128][KPAD];
  __shared__ ushort Vt[32][VTPAD];
  __shared__ ushort Pl[128][PPAD];

  const int bh = blockIdx.x;
  const int b = bh >> 2, hh = bh & 3;
  const size_t base = (size_t)b * (NL * ND) + hh * 32;
  const int tid = threadIdx.x;

  // stage K (rows) and V (transposed): 512 16B-chunks each
#pragma unroll
  for (int it = 0; it < 2; ++it) {
    const int ci = tid + (it << 8);
    const int row = ci >> 2, q = ci & 3;
    bf16x8 kv = *(const bf16x8*)(Kb + base + (size_t)row * ND + q * 8);
    *(bf16x8*)&Kl[row][q * 8] = kv;
    bf16x8 vv = *(const bf16x8*)(Vb + base + (size_t)row * ND + q * 8);
#pragma unroll
    for (int e = 0; e < 8; ++e) Vt[q * 8 + e][row] = (ushort)vv[e];
  }
  __syncthreads();

  const int w   = tid >> 6;
  const int l   = tid & 63;
  const int g   = l >> 4;
  const int r16 = l & 15;

  // phase 1: S = Q K^T / sqrt(dk) for rows [32w, 32w+32)
  bf16x8 qa[2];
#pragma unroll
  for (int t = 0; t < 2; ++t)
    qa[t] = *(const bf16x8*)(Qb + base + (size_t)(32 * w + 16 * t + r16) * ND + 8 * g);
  bf16x8 kbf[8];
#pragma unroll
  for (int c = 0; c < 8; ++c)
    kbf[c] = *(const bf16x8*)&Kl[16 * c + r16][8 * g];

  const f32x4 zero = {0.f, 0.f, 0.f, 0.f};
  f32x4 sacc[2][8];
#pragma unroll
  for (int t = 0; t < 2; ++t)
#pragma unroll
    for (int c = 0; c < 8; ++c)
      sacc[t][c] = __builtin_amdgcn_mfma_f32_16x16x32_bf16(qa[t], kbf[c], zero, 0, 0, 0);

  // phase 2: row softmax -> P (bf16)
  const float scale = 0.1767766952966369f;
#pragma unroll
  for (int t = 0; t < 2; ++t) {
#pragma unroll
    for (int r = 0; r < 4; ++r) {
      float s[8];
      float m = -1e30f;
#pragma unroll
      for (int c = 0; c < 8; ++c) { s[c] = sacc[t][c][r] * scale; m = fmaxf(m, s[c]); }
#pragma unroll
      for (int o = 1; o < 16; o <<= 1) m = fmaxf(m, __shfl_xor(m, o));
      float sum = 0.f;
#pragma unroll
      for (int c = 0; c < 8; ++c) { s[c] = __expf(s[c] - m); sum += s[c]; }
#pragma unroll
      for (int o = 1; o < 16; o <<= 1) sum += __shfl_xor(sum, o);
      const float inv = 1.0f / sum;
      const int row = 32 * w + 16 * t + 4 * g + r;
#pragma unroll
      for (int c = 0; c < 8; ++c)
        Pl[row][16 * c + r16] = f2bf(s[c] * inv);
    }
  }
  __syncthreads();

  // phase 3: O = P V
  f32x4 oacc[2][2] = {{zero, zero}, {zero, zero}};
#pragma unroll
  for (int ks = 0; ks < 4; ++ks) {
    bf16x8 pa[2], vbf[2];
#pragma unroll
    for (int t = 0; t < 2; ++t)
      pa[t] = *(const bf16x8*)&Pl[32 * w + 16 * t + r16][32 * ks + 8 * g];
#pragma unroll
    for (int cc = 0; cc < 2; ++cc)
      vbf[cc] = *(const bf16x8*)&Vt[16 * cc + r16][32 * ks + 8 * g];
#pragma unroll
    for (int t = 0; t < 2; ++t)
#pragma unroll
      for (int cc = 0; cc < 2; ++cc)
        oacc[t][cc] = __builtin_amdgcn_mfma_f32_16x16x32_bf16(pa[t], vbf[cc], oacc[t][cc], 0, 0, 0);
  }
  __syncthreads();

  // O via LDS (reuse Pl) for coalesced 16B stores
#pragma unroll
  for (int t = 0; t < 2; ++t)
#pragma unroll
    for (int cc = 0; cc < 2; ++cc)
#pragma unroll
      for (int r = 0; r < 4; ++r)
        Pl[32 * w + 16 * t + 4 * g + r][16 * cc + r16] = f2bf(oacc[t][cc][r]);
  __syncthreads();
#pragma unroll
  for (int i = 0; i < 2; ++i) {
    const int ci = l + 64 * i;
    const int row = 32 * w + (ci >> 2), q = ci & 3;
    bf16x8 v = *(const bf16x8*)&Pl[row][8 * q];
    *(bf16x8*)(O + base + (size_t)row * ND + q * 8) = v;
  }
}

// ------------------------------ event head ---------------------------------
__global__ __launch_bounds__(256) void event_head_kernel(
    const float* __restrict__ LA, const float* __restrict__ MB,
    const float* __restrict__ SB, float* __restrict__ out,
    uint32_t k0, uint32_t k1)
{
  int i = blockIdx.x * 256 + threadIdx.x;
  if (i >= NB * NT) return;
  int b = i >> 11, t = i & (NT - 1);
  size_t base = (size_t)b * (5 * NT) + t;
  float lg[5];
  float mx = -1e30f;
#pragma unroll
  for (int k = 0; k < 5; ++k) { lg[k] = LA[base + (size_t)k * NT]; mx = fmaxf(mx, lg[k]); }
  float se = 0.f;
#pragma unroll
  for (int k = 0; k < 5; ++k) { lg[k] = expf(lg[k] - mx); se += lg[k]; }
  float inv = 1.0f / se;
  float acc = 0.f;
#pragma unroll
  for (int k = 0; k < 5; ++k) {
    float nz = jax_normal_idx(k0, k1, (uint32_t)((b * 5 + k) * NT + t));
    float mean = MB[base + (size_t)k * NT];
    float sd   = expf(SB[base + (size_t)k * NT]);
    acc += (lg[k] * inv) * (mean + sd * nz);
  }
  out[i] = acc;
}

// ------------------------------- time head ---------------------------------
__global__ __launch_bounds__(64) void time_head_kernel(
    const float* __restrict__ X, const float* __restrict__ atw,
    const float* __restrict__ atb, const float* __restrict__ tmw,
    const float* __restrict__ tmb, const float* __restrict__ tsw,
    const float* __restrict__ tsb, float* __restrict__ out,
    uint32_t k0, uint32_t k1)
{
  const int b = blockIdx.x;
  const int l = threadIdx.x;
  const float* h = X + (size_t)b * (NL * ND);
  const float h0 = h[l], h1 = h[l + 64];
  float lg[5], tm[5], tsl[5];
#pragma unroll
  for (int k = 0; k < 5; ++k) {
    float s0 = fmaf(h0, atw[k * ND + l], h1 * atw[k * ND + l + 64]);
    float s1 = fmaf(h0, tmw[k * ND + l], h1 * tmw[k * ND + l + 64]);
    float s2 = fmaf(h0, tsw[k * ND + l], h1 * tsw[k * ND + l + 64]);
#pragma unroll
    for (int o = 32; o; o >>= 1) {
      s0 += __shfl_xor(s0, o);
      s1 += __shfl_xor(s1, o);
      s2 += __shfl_xor(s2, o);
    }
    lg[k] = s0 + atb[k]; tm[k] = s1 + tmb[k]; tsl[k] = s2 + tsb[k];
  }
  if (l == 0) {
    float mx = lg[0];
    for (int k = 1; k < 5; ++k) mx = fmaxf(mx, lg[k]);
    float se = 0.f;
    for (int k = 0; k < 5; ++k) { lg[k] = expf(lg[k] - mx); se += lg[k]; }
    float acc = 0.f;
    for (int k = 0; k < 5; ++k) {
      float nz = jax_normal_idx(k0, k1, (uint32_t)(b * 5 + k));
      acc += (lg[k] / se) * (tm[k] + expf(tsl[k]) * nz);
    }
    out[b] = acc;
  }
}

// ------------------------------ host driver --------------------------------
extern "C" void kernel_launch(void* const* d_in, const int* in_sizes, int n_in,
                              void* d_out, int out_size, void* d_ws, size_t ws_size,
                              hipStream_t stream)
{
  (void)in_sizes; (void)n_in; (void)out_size; (void)ws_size;

  const int*   ev      = (const int*)d_in[0];
  const int*   mask    = (const int*)d_in[2];
  const float* emb     = (const float*)d_in[4];
  const float* dec_wmu = (const float*)d_in[5];
  const float* dec_wls = (const float*)d_in[6];
  const float* dec_bmu = (const float*)d_in[7];
  const float* dec_bls = (const float*)d_in[8];
  const float* f1_wmu  = (const float*)d_in[9];
  const float* f1_wls  = (const float*)d_in[10];
  const float* f1_bmu  = (const float*)d_in[11];
  const float* f1_bls  = (const float*)d_in[12];
  const float* f2_wmu  = (const float*)d_in[13];
  const float* f2_wls  = (const float*)d_in[14];
  const float* f2_bmu  = (const float*)d_in[15];
  const float* f2_bls  = (const float*)d_in[16];
  const float* ln_g    = (const float*)d_in[17];
  const float* ln_b    = (const float*)d_in[18];
  const float* a_wmu   = (const float*)d_in[19];
  const float* a_wls   = (const float*)d_in[20];
  const float* a_bmu   = (const float*)d_in[21];
  const float* a_bls   = (const float*)d_in[22];
  const float* at_wmu  = (const float*)d_in[23];
  const float* at_wls  = (const float*)d_in[24];
  const float* at_bmu  = (const float*)d_in[25];
  const float* at_bls  = (const float*)d_in[26];
  const float* em_w    = (const float*)d_in[27];
  const float* em_b    = (const float*)d_in[28];
  const float* es_w    = (const float*)d_in[29];
  const float* es_b    = (const float*)d_in[30];
  const float* tm_w    = (const float*)d_in[31];
  const float* tm_b    = (const float*)d_in[32];
  const float* ts_w    = (const float*)d_in[33];
  const float* ts_b    = (const float*)d_in[34];

  float* ws = (float*)d_ws;
  const size_t SZ = (size_t)BL * ND;             // 8388608 floats / 32 MiB
  float*  X      = ws;                           // fp32 master activations
  ushort* Xbf    = (ushort*)(ws + SZ);
  ushort* INPXbf = (ushort*)(ws + SZ) + SZ;      // [1.5SZ,2SZ) as floats
  ushort* QBbf   = (ushort*)(ws + 2 * SZ);
  ushort* KBbf   = (ushort*)(ws + 2 * SZ) + SZ;
  ushort* VBbf   = (ushort*)(ws + 3 * SZ);
  ushort* T1bf   = (ushort*)(ws + 3 * SZ) + SZ;
  ushort* H1bf   = (ushort*)(ws + 4 * SZ);       // 65536x256 bf16 = full slot
  float*  LA     = ws + 5 * SZ;                  // 512x10240 fp32 (20 MiB)
  float*  MBo    = ws + 2 * SZ;                  // overlay (free at head stage)
  float*  SBo    = ws + 3 * SZ;                  // overlay
  ushort* EMWBF  = INPXbf;                       // overlay (free at head stage)
  ushort* ESWBF  = INPXbf + 1310720;
  ushort* WBF    = (ushort*)(ws + 6 * SZ);       // sampled weights bf16
  float*  WF32   = ws + 6 * SZ + BW_TOT / 2;     // sampled biases fp32
  ushort* Hb     = (ushort*)(WF32 + BF_TOT + 3); // h = x[:,0,:] bf16 (512x128)

  uint32_t fk0[46], fk1[46];
  for (uint32_t c = 0; c < 46; ++c) tf2x32(0u, 42u, 0u, c, fk0[c], fk1[c]);

  sample_all_kernel<<<dim3((SA_TOT + 255) / 256), dim3(256), 0, stream>>>(
      dec_wmu, dec_wls, dec_bmu, dec_bls,
      f1_wmu, f1_wls, f1_bmu, f1_bls,
      f2_wmu, f2_wls, f2_bmu, f2_bls,
      a_wmu, a_wls, a_bmu, a_bls,
      at_wmu, at_wls, at_bmu, at_bls, WBF, WF32);

  embed_pe_kernel<<<dim3((BL * ND) / 256), dim3(256), 0, stream>>>(
      ev, mask, emb, X, Xbf, INPXbf);

  for (int l = 0; l < 2; ++l) {
    for (int m = 0; m < 2; ++m) {
      const ushort* kvsrc = (m == 0) ? Xbf : INPXbf;
      const int s0 = l * 8 + m * 4;
      const ushort* Wq = WBF + BW_DEC + (size_t)(s0 + 0) * 16384;
      const ushort* Wk = WBF + BW_DEC + (size_t)(s0 + 1) * 16384;
      const ushort* Wv = WBF + BW_DEC + (size_t)(s0 + 2) * 16384;
      const ushort* Wo = WBF + BW_DEC + (size_t)(s0 + 3) * 16384;
      const float* Bq = WF32 + BF_DECB + (size_t)(s0 + 0) * 128;
      const float* Bk = WF32 + BF_DECB + (size_t)(s0 + 1) * 128;
      const float* Bv = WF32 + BF_DECB + (size_t)(s0 + 2) * 128;
      const float* Bo = WF32 + BF_DECB + (size_t)(s0 + 3) * 128;
      gemm_mfma<128, 1><<<dim3(1, 512), dim3(256), 0, stream>>>(
          Xbf, ND, Wq, Bq, nullptr, QBbf, nullptr, nullptr, nullptr, nullptr, ND);
      gemm_mfma<128, 1><<<dim3(1, 512), dim3(256), 0, stream>>>(
          kvsrc, ND, Wk, Bk, nullptr, KBbf, nullptr, nullptr, nullptr, nullptr, ND);
      gemm_mfma<128, 1><<<dim3(1, 512), dim3(256), 0, stream>>>(
          kvsrc, ND, Wv, Bv, nullptr, VBbf, nullptr, nullptr, nullptr, nullptr, ND);
      attn_mfma_kernel<<<dim3(NB * NH), dim3(256), 0, stream>>>(QBbf, KBbf, VBbf, T1bf);
      gemm_mfma<128, 3><<<dim3(1, 512), dim3(256), 0, stream>>>(
          T1bf, ND, Wo, Bo, X, Xbf, X,
          ln_g + (size_t)(l * 3 + m) * ND, ln_b + (size_t)(l * 3 + m) * ND,
          nullptr, ND);
    }
    gemm_mfma<128, 2><<<dim3(2, 512), dim3(256), 0, stream>>>(
        Xbf, ND, WBF + BW_F1 + (size_t)l * 32768, WF32 + BF_F1B + (size_t)l * 256,
        nullptr, H1bf, nullptr, nullptr, nullptr, nullptr, NDFF);
    gemm_mfma<256, 3><<<dim3(1, 512), dim3(256), 0, stream>>>(
        H1bf, NDFF, WBF + BW_F2 + (size_t)l * 32768, WF32 + BF_F2B + (size_t)l * 128,
        X, Xbf, X,
        ln_g + (size_t)(l * 3 + 2) * ND, ln_b + (size_t)(l * 3 + 2) * ND,
        (l == 1) ? Hb : nullptr, ND);
  }

  // head weight conversions (INPXbf region is free now)
  conv_bf16_kernel<<<dim3(5120), dim3(256), 0, stream>>>(em_w, EMWBF, 5 * NT * ND);
  conv_bf16_kernel<<<dim3(5120), dim3(256), 0, stream>>>(es_w, ESWBF, 5 * NT * ND);

  gemm_mfma<128, 0><<<dim3(80, 4), dim3(256), 0, stream>>>(
      Hb, ND, WBF + BW_AW, WF32 + BF_AB, LA, nullptr, nullptr, nullptr, nullptr,
      nullptr, 5 * NT);
  gemm_mfma<128, 0><<<dim3(80, 4), dim3(256), 0, stream>>>(
      Hb, ND, EMWBF, em_b, MBo, nullptr, nullptr, nullptr, nullptr, nullptr, 5 * NT);
  gemm_mfma<128, 0><<<dim3(80, 4), dim3(256), 0, stream>>>(
      Hb, ND, ESWBF, es_b, SBo, nullptr, nullptr, nullptr, nullptr, nullptr, 5 * NT);

  float* out = (float*)d_out;
  event_head_kernel<<<dim3((NB * NT) / 256), dim3(256), 0, stream>>>(
      LA, MBo, SBo, out, fk0[44], fk1[44]);
  time_head_kernel<<<dim3(NB), dim3(64), 0, stream>>>(
      X, WF32 + BF_ATW, WF32 + BF_ATB, tm_w, tm_b, ts_w, ts_b,
      out + (size_t)NB * NT, fk0[45], fk1[45]);
}

// Round 4
// 352.955 us; speedup vs baseline: 4.8204x; 1.3783x over previous
//
#include <hip/hip_runtime.h>
#include <cstdint>
#include <cstddef>

// ---------------------------------------------------------------------------
// HierarchicalNetwork: 2-layer Bayesian transformer decoder + mixture heads.
// B=512 L=128 D=128 H=4 dk=32 DFF=256 T=2048
// RNG: JAX threefry2x32 partitionable, fold_in(key(42), c) c=0..45 (verified).
// R4: per-b megakernels. attn_block = QKV proj + 4-head attention + Wo proj
// + residual/LN in ONE kernel (Q/K/V/P/O never leave LDS). ffn_block = FFN1
// + relu + FFN2 + residual/LN (H1 stays in LDS). Head GEMMs convert fp32
// weights inline. Numerics identical to R3 (same bf16 cast points).
// ---------------------------------------------------------------------------

#define NB   512
#define NL   128
#define ND   128
#define NH   4
#define NDFF 256
#define NT   2048
#define BL   (NB * NL)          // 65536 rows

typedef __attribute__((ext_vector_type(8))) short bf16x8;   // 8 bf16 in 4 VGPR
typedef __attribute__((ext_vector_type(4))) float f32x4;

// ----------------------------- threefry2x32 --------------------------------
__host__ __device__ __forceinline__ void tf2x32(uint32_t k0, uint32_t k1,
                                                uint32_t x0, uint32_t x1,
                                                uint32_t& o0, uint32_t& o1)
{
  const uint32_t ks2 = k0 ^ k1 ^ 0x1BD11BDAu;
  x0 += k0; x1 += k1;
#define TF_RND(r) { x0 += x1; x1 = (x1 << (r)) | (x1 >> (32 - (r))); x1 ^= x0; }
  TF_RND(13) TF_RND(15) TF_RND(26) TF_RND(6)
  x0 += k1;  x1 += ks2 + 1u;
  TF_RND(17) TF_RND(29) TF_RND(16) TF_RND(24)
  x0 += ks2; x1 += k0 + 2u;
  TF_RND(13) TF_RND(15) TF_RND(26) TF_RND(6)
  x0 += k0;  x1 += k1 + 3u;
  TF_RND(17) TF_RND(29) TF_RND(16) TF_RND(24)
  x0 += k1;  x1 += ks2 + 4u;
  TF_RND(13) TF_RND(15) TF_RND(26) TF_RND(6)
  x0 += ks2; x1 += k0 + 5u;
#undef TF_RND
  o0 = x0; o1 = x1;
}

// XLA f32 erfinv (Giles). _rn ops keep XLA's separate roundings (no contract).
__device__ __forceinline__ float erfinv32(float x)
{
  float w = -log1pf(-__fmul_rn(x, x));
  float p;
  if (w < 5.0f) {
    w = w - 2.5f;
    p = 2.81022636e-08f;
    p = __fadd_rn( 3.43273939e-07f, __fmul_rn(p, w));
    p = __fadd_rn(-3.5233877e-06f,  __fmul_rn(p, w));
    p = __fadd_rn(-4.39150654e-06f, __fmul_rn(p, w));
    p = __fadd_rn( 0.00021858087f,  __fmul_rn(p, w));
    p = __fadd_rn(-0.00125372503f,  __fmul_rn(p, w));
    p = __fadd_rn(-0.00417768164f,  __fmul_rn(p, w));
    p = __fadd_rn( 0.246640727f,    __fmul_rn(p, w));
    p = __fadd_rn( 1.50140941f,     __fmul_rn(p, w));
  } else {
    w = sqrtf(w) - 3.0f;
    p = -0.000200214257f;
    p = __fadd_rn( 0.000100950558f, __fmul_rn(p, w));
    p = __fadd_rn( 0.00134934322f,  __fmul_rn(p, w));
    p = __fadd_rn(-0.00367342844f,  __fmul_rn(p, w));
    p = __fadd_rn( 0.00573950773f,  __fmul_rn(p, w));
    p = __fadd_rn(-0.0076224613f,   __fmul_rn(p, w));
    p = __fadd_rn( 0.00943887047f,  __fmul_rn(p, w));
    p = __fadd_rn( 1.00167406f,     __fmul_rn(p, w));
    p = __fadd_rn( 2.83297682f,     __fmul_rn(p, w));
  }
  return __fmul_rn(p, x);
}

__device__ __forceinline__ float bits_to_normal(uint32_t bits)
{
  const float lo = -0.99999994f;
  float f = __uint_as_float((bits >> 9) | 0x3F800000u) - 1.0f;
  float u = __fadd_rn(__fmul_rn(f, 2.0f), lo);
  u = fmaxf(lo, u);
  return __fmul_rn(1.41421356f, erfinv32(u));
}

__device__ __forceinline__ float jax_normal_idx(uint32_t k0, uint32_t k1, uint32_t idx)
{
  uint32_t o0, o1;
  tf2x32(k0, k1, 0u, idx, o0, o1);
  return bits_to_normal(o0 ^ o1);
}

// RNE float->bf16 bits
__device__ __forceinline__ ushort f2bf(float f)
{
  uint32_t u = __float_as_uint(f);
  u += 0x7fffu + ((u >> 16) & 1u);
  return (ushort)(u >> 16);
}

// --------------------- fused Bayesian weight sampling ----------------------
#define SA_DECB 262144
#define SA_F1W  264192
#define SA_F1B  329728
#define SA_F2W  330240
#define SA_F2B  395776
#define SA_AW   396032
#define SA_AB   1706752
#define SA_ATW  1716992
#define SA_ATB  1717632
#define SA_TOT  1717637

#define BW_DEC  0
#define BW_F1   262144
#define BW_F2   327680
#define BW_AW   393216
#define BW_TOT  1703936

#define BF_DECB 0
#define BF_F1B  2048
#define BF_F2B  2560
#define BF_AB   2816
#define BF_ATW  13056
#define BF_ATB  13696
#define BF_TOT  13701

__global__ __launch_bounds__(256) void sample_all_kernel(
    const float* __restrict__ dec_wmu, const float* __restrict__ dec_wls,
    const float* __restrict__ dec_bmu, const float* __restrict__ dec_bls,
    const float* __restrict__ f1_wmu,  const float* __restrict__ f1_wls,
    const float* __restrict__ f1_bmu,  const float* __restrict__ f1_bls,
    const float* __restrict__ f2_wmu,  const float* __restrict__ f2_wls,
    const float* __restrict__ f2_bmu,  const float* __restrict__ f2_bls,
    const float* __restrict__ a_wmu,   const float* __restrict__ a_wls,
    const float* __restrict__ a_bmu,   const float* __restrict__ a_bls,
    const float* __restrict__ at_wmu,  const float* __restrict__ at_wls,
    const float* __restrict__ at_bmu,  const float* __restrict__ at_bls,
    ushort* __restrict__ wbf, float* __restrict__ wf32)
{
  const int i = blockIdx.x * 256 + threadIdx.x;
  if (i >= SA_TOT) return;
  const float* mu; const float* ls;
  uint32_t c, idx;
  int bf_dst = -1, f32_dst = -1;
  if (i < SA_DECB) {
    int s = i >> 14;
    mu = dec_wmu + i; ls = dec_wls + i;
    c = 2u * s + (s >= 8 ? 4u : 0u); idx = (uint32_t)(i & 16383);
    bf_dst = BW_DEC + i;
  } else if (i < SA_F1W) {
    int t = i - SA_DECB; int s = t >> 7;
    mu = dec_bmu + t; ls = dec_bls + t;
    c = 2u * s + 1u + (s >= 8 ? 4u : 0u); idx = (uint32_t)(t & 127);
    f32_dst = BF_DECB + t;
  } else if (i < SA_F1B) {
    int t = i - SA_F1W; int s = t >> 15;
    mu = f1_wmu + t; ls = f1_wls + t;
    c = 16u + 20u * s; idx = (uint32_t)(t & 32767);
    bf_dst = BW_F1 + t;
  } else if (i < SA_F2W) {
    int t = i - SA_F1B; int s = t >> 8;
    mu = f1_bmu + t; ls = f1_bls + t;
    c = 17u + 20u * s; idx = (uint32_t)(t & 255);
    f32_dst = BF_F1B + t;
  } else if (i < SA_F2B) {
    int t = i - SA_F2W; int s = t >> 15;
    mu = f2_wmu + t; ls = f2_wls + t;
    c = 18u + 20u * s; idx = (uint32_t)(t & 32767);
    bf_dst = BW_F2 + t;
  } else if (i < SA_AW) {
    int t = i - SA_F2B; int s = t >> 7;
    mu = f2_bmu + t; ls = f2_bls + t;
    c = 19u + 20u * s; idx = (uint32_t)(t & 127);
    f32_dst = BF_F2B + t;
  } else if (i < SA_AB) {
    int t = i - SA_AW;
    mu = a_wmu + t; ls = a_wls + t; c = 40u; idx = (uint32_t)t;
    bf_dst = BW_AW + t;
  } else if (i < SA_ATW) {
    int t = i - SA_AB;
    mu = a_bmu + t; ls = a_bls + t; c = 41u; idx = (uint32_t)t;
    f32_dst = BF_AB + t;
  } else if (i < SA_ATB) {
    int t = i - SA_ATW;
    mu = at_wmu + t; ls = at_wls + t; c = 42u; idx = (uint32_t)t;
    f32_dst = BF_ATW + t;
  } else {
    int t = i - SA_ATB;
    mu = at_bmu + t; ls = at_bls + t; c = 43u; idx = (uint32_t)t;
    f32_dst = BF_ATB + t;
  }
  uint32_t k0, k1;
  tf2x32(0u, 42u, 0u, c, k0, k1);
  float v = mu[0] + expf(ls[0]) * jax_normal_idx(k0, k1, idx);
  if (bf_dst >= 0) wbf[bf_dst] = f2bf(v);
  else             wf32[f32_dst] = v;
}

// --------------------------- embedding + pos-enc ---------------------------
__global__ __launch_bounds__(256) void embed_pe_kernel(
    const int* __restrict__ ev, const int* __restrict__ mask,
    const float* __restrict__ emb, float* __restrict__ X,
    ushort* __restrict__ Xbf, ushort* __restrict__ INPXbf)
{
  int i = blockIdx.x * 256 + threadIdx.x;
  if (i >= BL * ND) return;
  int d  = i & (ND - 1);
  int bl = i >> 7;
  int e  = ev[bl];
  int mk = mask[bl];
  float x   = emb[(size_t)e * ND + d];
  float div = expf((float)d * (float)(-9.210340371976184 / 128.0));
  float ang = (float)mk * div;
  float pe  = ((mk & 1) == 0) ? sinf(ang) : cosf(ang);
  X[i]      = x;
  Xbf[i]    = f2bf(x);
  INPXbf[i] = f2bf(x + pe);
}

// ------------------- per-b fused attention block kernel --------------------
// One block per b. 512 threads = 8 waves; wave w owns rows [16w,16w+16).
// LDS: Wl (current weight), Kt (K), Vt (V^T), B0 (Q then O). P uses Wl.
// acc[c][r] convention: row 16w+4g+r, col 16c+r16 (16x16x32 C/D layout).
#define STR 136   // LDS row stride in ushorts (272 B, 16B-aligned)

template<int CROSS>
__global__ __launch_bounds__(512) void attn_block_kernel(
    const ushort* __restrict__ Xbf, const ushort* __restrict__ KVsrc,
    float* __restrict__ X, ushort* __restrict__ Xout,
    const ushort* __restrict__ W4,   // Wq|Wk|Wv|Wo, each 128x128 bf16
    const float* __restrict__ B4,    // Bq|Bk|Bv|Bo, each 128 fp32
    const float* __restrict__ lng, const float* __restrict__ lnb)
{
  __shared__ ushort Wl[128][STR];
  __shared__ ushort Kt[128][STR];
  __shared__ ushort Vt[128][STR];
  __shared__ ushort B0[128][STR];

  const int b = blockIdx.x;
  const int tid = threadIdx.x;
  const int w = tid >> 6, l = tid & 63;
  const int g = l >> 4, r16 = l & 15;
  const size_t abase = (size_t)b * (NL * ND);
  const ushort* Aq  = Xbf + abase;
  const ushort* Akv = (CROSS ? KVsrc : Xbf) + abase;
  const f32x4 zero = {0.f, 0.f, 0.f, 0.f};

  // stage a 128x128 bf16 weight into Wl
  auto stageW = [&](const ushort* src) {
#pragma unroll
    for (int it = 0; it < 4; ++it) {
      int ci = tid + it * 512;
      int row = ci >> 4, q = ci & 15;
      *(bf16x8*)&Wl[row][q * 8] = *(const bf16x8*)(src + (size_t)row * 128 + q * 8);
    }
  };
  // 128x128 GEMM vs Wl, A from global (this wave's 16 rows)
  auto gemmG = [&](const ushort* A, f32x4 (&acc)[8]) {
#pragma unroll
    for (int c = 0; c < 8; ++c) acc[c] = zero;
#pragma unroll
    for (int ks = 0; ks < 4; ++ks) {
      bf16x8 a = *(const bf16x8*)(A + (size_t)(16 * w + r16) * 128 + 32 * ks + 8 * g);
#pragma unroll
      for (int c = 0; c < 8; ++c) {
        bf16x8 wv = *(const bf16x8*)&Wl[16 * c + r16][32 * ks + 8 * g];
        acc[c] = __builtin_amdgcn_mfma_f32_16x16x32_bf16(a, wv, acc[c], 0, 0, 0);
      }
    }
  };

  f32x4 acc[8];

  // ---- Q = Xbf @ Wq^T + Bq -> B0 ----
  stageW(W4 + 0 * 16384);
  __syncthreads();
  gemmG(Aq, acc);
#pragma unroll
  for (int c = 0; c < 8; ++c) {
    float bb = B4[0 * 128 + 16 * c + r16];
#pragma unroll
    for (int r = 0; r < 4; ++r)
      B0[16 * w + 4 * g + r][16 * c + r16] = f2bf(acc[c][r] + bb);
  }
  __syncthreads();

  // ---- K = kv @ Wk^T + Bk -> Kt ----
  stageW(W4 + 1 * 16384);
  __syncthreads();
  gemmG(Akv, acc);
#pragma unroll
  for (int c = 0; c < 8; ++c) {
    float bb = B4[1 * 128 + 16 * c + r16];
#pragma unroll
    for (int r = 0; r < 4; ++r)
      Kt[16 * w + 4 * g + r][16 * c + r16] = f2bf(acc[c][r] + bb);
  }
  __syncthreads();

  // ---- V = kv @ Wv^T + Bv -> Vt (transposed: Vt[d][l]) ----
  stageW(W4 + 2 * 16384);
  __syncthreads();
  gemmG(Akv, acc);
#pragma unroll
  for (int c = 0; c < 8; ++c) {
    float bb = B4[2 * 128 + 16 * c + r16];
#pragma unroll
    for (int r = 0; r < 4; ++r)
      Vt[16 * c + r16][16 * w + 4 * g + r] = f2bf(acc[c][r] + bb);
  }
  __syncthreads();   // Kt, Vt published; Wl free (P buffer)

  // ---- attention: wave w handles rows [16w,16w+16), heads 0..3 ----
  const float scale = 0.1767766952966369f;   // 1/sqrt(32)
  f32x4 oacc[4][2];
#pragma unroll
  for (int h = 0; h < 4; ++h) { oacc[h][0] = zero; oacc[h][1] = zero; }

#pragma unroll
  for (int h = 0; h < 4; ++h) {
    bf16x8 qa = *(const bf16x8*)&B0[16 * w + r16][32 * h + 8 * g];
    f32x4 s[8];
#pragma unroll
    for (int c = 0; c < 8; ++c) {
      bf16x8 kv = *(const bf16x8*)&Kt[16 * c + r16][32 * h + 8 * g];
      s[c] = __builtin_amdgcn_mfma_f32_16x16x32_bf16(qa, kv, zero, 0, 0, 0);
    }
    // row softmax (row = 16w+4g+r; reduce across the 16 r16-lanes)
#pragma unroll
    for (int r = 0; r < 4; ++r) {
      float v[8]; float m = -1e30f;
#pragma unroll
      for (int c = 0; c < 8; ++c) { v[c] = s[c][r] * scale; m = fmaxf(m, v[c]); }
#pragma unroll
      for (int o = 1; o < 16; o <<= 1) m = fmaxf(m, __shfl_xor(m, o));
      float sum = 0.f;
#pragma unroll
      for (int c = 0; c < 8; ++c) { v[c] = __expf(v[c] - m); sum += v[c]; }
#pragma unroll
      for (int o = 1; o < 16; o <<= 1) sum += __shfl_xor(sum, o);
      const float inv = 1.0f / sum;
#pragma unroll
      for (int c = 0; c < 8; ++c)
        Wl[16 * w + 4 * g + r][16 * c + r16] = f2bf(v[c] * inv);   // P (wave-local)
    }
    // PV: O[rows][32h+16cc+r16] += P @ V
#pragma unroll
    for (int ks = 0; ks < 4; ++ks) {
      bf16x8 pa = *(const bf16x8*)&Wl[16 * w + r16][32 * ks + 8 * g];
#pragma unroll
      for (int cc = 0; cc < 2; ++cc) {
        bf16x8 vv = *(const bf16x8*)&Vt[32 * h + 16 * cc + r16][32 * ks + 8 * g];
        oacc[h][cc] = __builtin_amdgcn_mfma_f32_16x16x32_bf16(pa, vv, oacc[h][cc], 0, 0, 0);
      }
    }
  }

  // ---- O -> B0 (overwrites this wave's Q rows; Q fully consumed) ----
#pragma unroll
  for (int h = 0; h < 4; ++h)
#pragma unroll
    for (int cc = 0; cc < 2; ++cc)
#pragma unroll
      for (int r = 0; r < 4; ++r)
        B0[16 * w + 4 * g + r][32 * h + 16 * cc + r16] = f2bf(oacc[h][cc][r]);
  __syncthreads();   // everyone done with Wl(P) and B0 writes

  // ---- out-proj: C = O @ Wo^T + Bo, then residual + LN ----
  stageW(W4 + 3 * 16384);
  __syncthreads();
  f32x4 acc2[8];
#pragma unroll
  for (int c = 0; c < 8; ++c) acc2[c] = zero;
#pragma unroll
  for (int ks = 0; ks < 4; ++ks) {
    bf16x8 a = *(const bf16x8*)&B0[16 * w + r16][32 * ks + 8 * g];
#pragma unroll
    for (int c = 0; c < 8; ++c) {
      bf16x8 wv = *(const bf16x8*)&Wl[16 * c + r16][32 * ks + 8 * g];
      acc2[c] = __builtin_amdgcn_mfma_f32_16x16x32_bf16(a, wv, acc2[c], 0, 0, 0);
    }
  }

  float gg[8], lb[8], bo[8];
#pragma unroll
  for (int c = 0; c < 8; ++c) {
    gg[c] = lng[16 * c + r16];
    lb[c] = lnb[16 * c + r16];
    bo[c] = B4[3 * 128 + 16 * c + r16];
  }
#pragma unroll
  for (int r = 0; r < 4; ++r) {
    const int row = 16 * w + 4 * g + r;
    const size_t gr = abase + (size_t)row * ND;
    float xv[8];
#pragma unroll
    for (int c = 0; c < 8; ++c)
      xv[c] = acc2[c][r] + bo[c] + X[gr + 16 * c + r16];
    float s = 0.f;
#pragma unroll
    for (int c = 0; c < 8; ++c) s += xv[c];
#pragma unroll
    for (int o = 1; o < 16; o <<= 1) s += __shfl_xor(s, o);
    const float mean = s * (1.0f / 128.0f);
    float q = 0.f;
#pragma unroll
    for (int c = 0; c < 8; ++c) { float d = xv[c] - mean; q += d * d; }
#pragma unroll
    for (int o = 1; o < 16; o <<= 1) q += __shfl_xor(q, o);
    const float inv = 1.0f / sqrtf(q * (1.0f / 128.0f) + 1e-5f);
#pragma unroll
    for (int c = 0; c < 8; ++c) {
      float o = (xv[c] - mean) * inv * gg[c] + lb[c];
      X[gr + 16 * c + r16] = o;
      Xout[gr + 16 * c + r16] = f2bf(o);
    }
  }
}

// ---------------------- per-b fused FFN block kernel -----------------------
// H1 = relu(X@W1^T+b1) [128x256] lives in LDS (two 128-col halves);
// F = H1@W2^T+b2; then residual + LN. W buffer reused W1 -> W2.
__global__ __launch_bounds__(512) void ffn_block_kernel(
    const ushort* __restrict__ Xbf, float* __restrict__ X, ushort* __restrict__ Xout,
    const ushort* __restrict__ W1, const float* __restrict__ B1,
    const ushort* __restrict__ W2, const float* __restrict__ B2,
    const float* __restrict__ lng, const float* __restrict__ lnb,
    ushort* __restrict__ Hb)
{
  __shared__ ushort Wa[128][STR];   // W1 rows 0-127   | W2 k 0-127
  __shared__ ushort Wb[128][STR];   // W1 rows 128-255 | W2 k 128-255
  __shared__ ushort Ha[128][STR];   // H1 cols 0-127
  __shared__ ushort Hc[128][STR];   // H1 cols 128-255

  const int b = blockIdx.x;
  const int tid = threadIdx.x;
  const int w = tid >> 6, l = tid & 63;
  const int g = l >> 4, r16 = l & 15;
  const size_t abase = (size_t)b * (NL * ND);
  const ushort* A = Xbf + abase;
  const f32x4 zero = {0.f, 0.f, 0.f, 0.f};

  // stage W1 (256 rows x 128)
#pragma unroll
  for (int it = 0; it < 8; ++it) {
    int ci = tid + it * 512;
    int row = ci >> 4, q = ci & 15;
    bf16x8 v = *(const bf16x8*)(W1 + (size_t)row * 128 + q * 8);
    if (row < 128) *(bf16x8*)&Wa[row][q * 8] = v;
    else           *(bf16x8*)&Wb[row - 128][q * 8] = v;
  }
  __syncthreads();

  // H1 GEMM: 16 n-frags
  f32x4 acc1[16];
#pragma unroll
  for (int c = 0; c < 16; ++c) acc1[c] = zero;
#pragma unroll
  for (int ks = 0; ks < 4; ++ks) {
    bf16x8 a = *(const bf16x8*)(A + (size_t)(16 * w + r16) * 128 + 32 * ks + 8 * g);
#pragma unroll
    for (int c = 0; c < 16; ++c) {
      bf16x8 wv = (c < 8)
        ? *(const bf16x8*)&Wa[16 * c + r16][32 * ks + 8 * g]
        : *(const bf16x8*)&Wb[16 * (c - 8) + r16][32 * ks + 8 * g];
      acc1[c] = __builtin_amdgcn_mfma_f32_16x16x32_bf16(a, wv, acc1[c], 0, 0, 0);
    }
  }
  // relu + bias -> H1 (wave-local rows)
#pragma unroll
  for (int c = 0; c < 16; ++c) {
    float bb = B1[16 * c + r16];
#pragma unroll
    for (int r = 0; r < 4; ++r) {
      float o = fmaxf(acc1[c][r] + bb, 0.f);
      if (c < 8) Ha[16 * w + 4 * g + r][16 * c + r16] = f2bf(o);
      else       Hc[16 * w + 4 * g + r][16 * (c - 8) + r16] = f2bf(o);
    }
  }
  __syncthreads();   // all waves done reading W1

  // stage W2 (128 rows x 256) into Wa (k<128) / Wb (k>=128)
#pragma unroll
  for (int it = 0; it < 8; ++it) {
    int ci = tid + it * 512;
    int row = ci >> 5, q = ci & 31;
    bf16x8 v = *(const bf16x8*)(W2 + (size_t)row * 256 + q * 8);
    if (q < 16) *(bf16x8*)&Wa[row][q * 8] = v;
    else        *(bf16x8*)&Wb[row][(q - 16) * 8] = v;
  }
  __syncthreads();

  // F GEMM: K=256 (8 k-steps)
  f32x4 acc2[8];
#pragma unroll
  for (int c = 0; c < 8; ++c) acc2[c] = zero;
#pragma unroll
  for (int ks = 0; ks < 8; ++ks) {
    bf16x8 a = (ks < 4)
      ? *(const bf16x8*)&Ha[16 * w + r16][32 * ks + 8 * g]
      : *(const bf16x8*)&Hc[16 * w + r16][32 * (ks - 4) + 8 * g];
#pragma unroll
    for (int c = 0; c < 8; ++c) {
      bf16x8 wv = (ks < 4)
        ? *(const bf16x8*)&Wa[16 * c + r16][32 * ks + 8 * g]
        : *(const bf16x8*)&Wb[16 * c + r16][32 * (ks - 4) + 8 * g];
      acc2[c] = __builtin_amdgcn_mfma_f32_16x16x32_bf16(a, wv, acc2[c], 0, 0, 0);
    }
  }

  float gg[8], lb[8], bo[8];
#pragma unroll
  for (int c = 0; c < 8; ++c) {
    gg[c] = lng[16 * c + r16];
    lb[c] = lnb[16 * c + r16];
    bo[c] = B2[16 * c + r16];
  }
#pragma unroll
  for (int r = 0; r < 4; ++r) {
    const int row = 16 * w + 4 * g + r;
    const size_t gr = abase + (size_t)row * ND;
    float xv[8];
#pragma unroll
    for (int c = 0; c < 8; ++c)
      xv[c] = acc2[c][r] + bo[c] + X[gr + 16 * c + r16];
    float s = 0.f;
#pragma unroll
    for (int c = 0; c < 8; ++c) s += xv[c];
#pragma unroll
    for (int o = 1; o < 16; o <<= 1) s += __shfl_xor(s, o);
    const float mean = s * (1.0f / 128.0f);
    float q = 0.f;
#pragma unroll
    for (int c = 0; c < 8; ++c) { float d = xv[c] - mean; q += d * d; }
#pragma unroll
    for (int o = 1; o < 16; o <<= 1) q += __shfl_xor(q, o);
    const float inv = 1.0f / sqrtf(q * (1.0f / 128.0f) + 1e-5f);
#pragma unroll
    for (int c = 0; c < 8; ++c) {
      float o = (xv[c] - mean) * inv * gg[c] + lb[c];
      X[gr + 16 * c + r16] = o;
      Xout[gr + 16 * c + r16] = f2bf(o);
      if (Hb && row == 0)
        Hb[(size_t)b * ND + 16 * c + r16] = f2bf(o);
    }
  }
}

// ------------------------------ head GEMM ----------------------------------
// C[M=512, N] tile 128x128, A bf16 (Hb), W bf16 or fp32 (converted in stage).
template<int WFP32>
__global__ __launch_bounds__(256) void head_gemm(
    const ushort* __restrict__ A,
    const ushort* __restrict__ Wb16, const float* __restrict__ Wf32,
    const float* __restrict__ bias, float* __restrict__ C, int ldc)
{
  __shared__ char smem[128 * 132 * 4];   // W view (bf16) then C view (fp32)
  ushort (*Wl)[STR] = (ushort(*)[STR])smem;   // 128x136 fits in 67.5KB? 128*136*2=34816 <= sized
  float  (*Cl)[132] = (float(*)[132])smem;

  const int tid = threadIdx.x;
  const int bn = blockIdx.x * 128;
  const int bm = blockIdx.y * 128;
  const int w = tid >> 6, l = tid & 63;
  const int r16 = l & 15, g = l >> 4;
  const f32x4 zero = {0.f, 0.f, 0.f, 0.f};

  // stage W rows [bn, bn+128): 2048 8-elem chunks
#pragma unroll
  for (int it = 0; it < 8; ++it) {
    int ci = tid + it * 256;
    int row = ci >> 4, q = ci & 15;
    if (WFP32) {
      float4 v0 = *(const float4*)(Wf32 + (size_t)(bn + row) * 128 + q * 8);
      float4 v1 = *(const float4*)(Wf32 + (size_t)(bn + row) * 128 + q * 8 + 4);
      bf16x8 o;
      o[0] = f2bf(v0.x); o[1] = f2bf(v0.y); o[2] = f2bf(v0.z); o[3] = f2bf(v0.w);
      o[4] = f2bf(v1.x); o[5] = f2bf(v1.y); o[6] = f2bf(v1.z); o[7] = f2bf(v1.w);
      *(bf16x8*)&Wl[row][q * 8] = o;
    } else {
      *(bf16x8*)&Wl[row][q * 8] =
          *(const bf16x8*)(Wb16 + (size_t)(bn + row) * 128 + q * 8);
    }
  }
  __syncthreads();

  // 2 m-frags (rows 32w+16t+r16), 8 n-frags, 4 k-steps
  f32x4 acc[2][8];
#pragma unroll
  for (int t = 0; t < 2; ++t)
#pragma unroll
    for (int c = 0; c < 8; ++c) acc[t][c] = zero;
#pragma unroll
  for (int ks = 0; ks < 4; ++ks) {
    bf16x8 a[2];
#pragma unroll
    for (int t = 0; t < 2; ++t)
      a[t] = *(const bf16x8*)(A + (size_t)(bm + 32 * w + 16 * t + r16) * 128
                              + 32 * ks + 8 * g);
    bf16x8 wv[8];
#pragma unroll
    for (int c = 0; c < 8; ++c)
      wv[c] = *(const bf16x8*)&Wl[16 * c + r16][32 * ks + 8 * g];
#pragma unroll
    for (int t = 0; t < 2; ++t)
#pragma unroll
      for (int c = 0; c < 8; ++c)
        acc[t][c] = __builtin_amdgcn_mfma_f32_16x16x32_bf16(a[t], wv[c], acc[t][c], 0, 0, 0);
  }

  float bcol[8];
#pragma unroll
  for (int c = 0; c < 8; ++c) bcol[c] = bias[bn + 16 * c + r16];
  __syncthreads();

#pragma unroll
  for (int t = 0; t < 2; ++t)
#pragma unroll
    for (int c = 0; c < 8; ++c)
#pragma unroll
      for (int r = 0; r < 4; ++r)
        Cl[32 * w + 16 * t + 4 * g + r][16 * c + r16] = acc[t][c][r] + bcol[c];
  __syncthreads();
#pragma unroll
  for (int i = 0; i < 16; ++i) {
    int ci = l + 64 * i;
    int row = 32 * w + (ci >> 5), q = ci & 31;
    float4 v = *(const float4*)&Cl[row][4 * q];
    *(float4*)(C + (size_t)(bm + row) * ldc + bn + 4 * q) = v;
  }
}

// ------------------------------ event head ---------------------------------
__global__ __launch_bounds__(256) void event_head_kernel(
    const float* __restrict__ LA, const float* __restrict__ MB,
    const float* __restrict__ SB, float* __restrict__ out,
    uint32_t k0, uint32_t k1)
{
  int i = blockIdx.x * 256 + threadIdx.x;
  if (i >= NB * NT) return;
  int b = i >> 11, t = i & (NT - 1);
  size_t base = (size_t)b * (5 * NT) + t;
  float lg[5];
  float mx = -1e30f;
#pragma unroll
  for (int k = 0; k < 5; ++k) { lg[k] = LA[base + (size_t)k * NT]; mx = fmaxf(mx, lg[k]); }
  float se = 0.f;
#pragma unroll
  for (int k = 0; k < 5; ++k) { lg[k] = expf(lg[k] - mx); se += lg[k]; }
  float inv = 1.0f / se;
  float acc = 0.f;
#pragma unroll
  for (int k = 0; k < 5; ++k) {
    float nz = jax_normal_idx(k0, k1, (uint32_t)((b * 5 + k) * NT + t));
    float mean = MB[base + (size_t)k * NT];
    float sd   = expf(SB[base + (size_t)k * NT]);
    acc += (lg[k] * inv) * (mean + sd * nz);
  }
  out[i] = acc;
}

// ------------------------------- time head ---------------------------------
__global__ __launch_bounds__(64) void time_head_kernel(
    const float* __restrict__ X, const float* __restrict__ atw,
    const float* __restrict__ atb, const float* __restrict__ tmw,
    const float* __restrict__ tmb, const float* __restrict__ tsw,
    const float* __restrict__ tsb, float* __restrict__ out,
    uint32_t k0, uint32_t k1)
{
  const int b = blockIdx.x;
  const int l = threadIdx.x;
  const float* h = X + (size_t)b * (NL * ND);
  const float h0 = h[l], h1 = h[l + 64];
  float lg[5], tm[5], tsl[5];
#pragma unroll
  for (int k = 0; k < 5; ++k) {
    float s0 = fmaf(h0, atw[k * ND + l], h1 * atw[k * ND + l + 64]);
    float s1 = fmaf(h0, tmw[k * ND + l], h1 * tmw[k * ND + l + 64]);
    float s2 = fmaf(h0, tsw[k * ND + l], h1 * tsw[k * ND + l + 64]);
#pragma unroll
    for (int o = 32; o; o >>= 1) {
      s0 += __shfl_xor(s0, o);
      s1 += __shfl_xor(s1, o);
      s2 += __shfl_xor(s2, o);
    }
    lg[k] = s0 + atb[k]; tm[k] = s1 + tmb[k]; tsl[k] = s2 + tsb[k];
  }
  if (l == 0) {
    float mx = lg[0];
    for (int k = 1; k < 5; ++k) mx = fmaxf(mx, lg[k]);
    float se = 0.f;
    for (int k = 0; k < 5; ++k) { lg[k] = expf(lg[k] - mx); se += lg[k]; }
    float acc = 0.f;
    for (int k = 0; k < 5; ++k) {
      float nz = jax_normal_idx(k0, k1, (uint32_t)(b * 5 + k));
      acc += (lg[k] / se) * (tm[k] + expf(tsl[k]) * nz);
    }
    out[b] = acc;
  }
}

// ------------------------------ host driver --------------------------------
extern "C" void kernel_launch(void* const* d_in, const int* in_sizes, int n_in,
                              void* d_out, int out_size, void* d_ws, size_t ws_size,
                              hipStream_t stream)
{
  (void)in_sizes; (void)n_in; (void)out_size; (void)ws_size;

  const int*   ev      = (const int*)d_in[0];
  const int*   mask    = (const int*)d_in[2];
  const float* emb     = (const float*)d_in[4];
  const float* dec_wmu = (const float*)d_in[5];
  const float* dec_wls = (const float*)d_in[6];
  const float* dec_bmu = (const float*)d_in[7];
  const float* dec_bls = (const float*)d_in[8];
  const float* f1_wmu  = (const float*)d_in[9];
  const float* f1_wls  = (const float*)d_in[10];
  const float* f1_bmu  = (const float*)d_in[11];
  const float* f1_bls  = (const float*)d_in[12];
  const float* f2_wmu  = (const float*)d_in[13];
  const float* f2_wls  = (const float*)d_in[14];
  const float* f2_bmu  = (const float*)d_in[15];
  const float* f2_bls  = (const float*)d_in[16];
  const float* ln_g    = (const float*)d_in[17];
  const float* ln_b    = (const float*)d_in[18];
  const float* a_wmu   = (const float*)d_in[19];
  const float* a_wls   = (const float*)d_in[20];
  const float* a_bmu   = (const float*)d_in[21];
  const float* a_bls   = (const float*)d_in[22];
  const float* at_wmu  = (const float*)d_in[23];
  const float* at_wls  = (const float*)d_in[24];
  const float* at_bmu  = (const float*)d_in[25];
  const float* at_bls  = (const float*)d_in[26];
  const float* em_w    = (const float*)d_in[27];
  const float* em_b    = (const float*)d_in[28];
  const float* es_w    = (const float*)d_in[29];
  const float* es_b    = (const float*)d_in[30];
  const float* tm_w    = (const float*)d_in[31];
  const float* tm_b    = (const float*)d_in[32];
  const float* ts_w    = (const float*)d_in[33];
  const float* ts_b    = (const float*)d_in[34];

  float* ws = (float*)d_ws;
  const size_t SZ = (size_t)BL * ND;             // 8,388,608
  const size_t HN = (size_t)NB * 5 * NT;         // 5,242,880
  float*  X      = ws;                           // fp32 master [SZ]
  ushort* Xbf    = (ushort*)(ws + SZ);           // [SZ] ushorts
  ushort* INPXbf = (ushort*)(ws + SZ) + SZ;      // [SZ] ushorts
  float*  LA     = ws + 2 * SZ;                  // [HN]
  float*  MBo    = LA + HN;
  float*  SBo    = MBo + HN;
  ushort* WBF    = (ushort*)(SBo + HN);          // [BW_TOT]
  float*  WF32   = SBo + HN + BW_TOT / 2;        // [BF_TOT]
  ushort* Hbuf   = (ushort*)(WF32 + BF_TOT + 3); // [NB*ND]

  uint32_t fk0[46], fk1[46];
  for (uint32_t c = 0; c < 46; ++c) tf2x32(0u, 42u, 0u, c, fk0[c], fk1[c]);

  sample_all_kernel<<<dim3((SA_TOT + 255) / 256), dim3(256), 0, stream>>>(
      dec_wmu, dec_wls, dec_bmu, dec_bls,
      f1_wmu, f1_wls, f1_bmu, f1_bls,
      f2_wmu, f2_wls, f2_bmu, f2_bls,
      a_wmu, a_wls, a_bmu, a_bls,
      at_wmu, at_wls, at_bmu, at_bls, WBF, WF32);

  embed_pe_kernel<<<dim3((BL * ND) / 256), dim3(256), 0, stream>>>(
      ev, mask, emb, X, Xbf, INPXbf);

  for (int l = 0; l < 2; ++l) {
    const int s_self = l * 8, s_cross = l * 8 + 4;
    attn_block_kernel<0><<<dim3(NB), dim3(512), 0, stream>>>(
        Xbf, nullptr, X, Xbf,
        WBF + BW_DEC + (size_t)s_self * 16384,
        WF32 + BF_DECB + (size_t)s_self * 128,
        ln_g + (size_t)(l * 3 + 0) * ND, ln_b + (size_t)(l * 3 + 0) * ND);
    attn_block_kernel<1><<<dim3(NB), dim3(512), 0, stream>>>(
        Xbf, INPXbf, X, Xbf,
        WBF + BW_DEC + (size_t)s_cross * 16384,
        WF32 + BF_DECB + (size_t)s_cross * 128,
        ln_g + (size_t)(l * 3 + 1) * ND, ln_b + (size_t)(l * 3 + 1) * ND);
    ffn_block_kernel<<<dim3(NB), dim3(512), 0, stream>>>(
        Xbf, X, Xbf,
        WBF + BW_F1 + (size_t)l * 32768, WF32 + BF_F1B + (size_t)l * 256,
        WBF + BW_F2 + (size_t)l * 32768, WF32 + BF_F2B + (size_t)l * 128,
        ln_g + (size_t)(l * 3 + 2) * ND, ln_b + (size_t)(l * 3 + 2) * ND,
        (l == 1) ? Hbuf : nullptr);
  }

  head_gemm<0><<<dim3(80, 4), dim3(256), 0, stream>>>(
      Hbuf, WBF + BW_AW, nullptr, WF32 + BF_AB, LA, 5 * NT);
  head_gemm<1><<<dim3(80, 4), dim3(256), 0, stream>>>(
      Hbuf, nullptr, em_w, em_b, MBo, 5 * NT);
  head_gemm<1><<<dim3(80, 4), dim3(256), 0, stream>>>(
      Hbuf, nullptr, es_w, es_b, SBo, 5 * NT);

  float* out = (float*)d_out;
  event_head_kernel<<<dim3((NB * NT) / 256), dim3(256), 0, stream>>>(
      LA, MBo, SBo, out, fk0[44], fk1[44]);
  time_head_kernel<<<dim3(NB), dim3(64), 0, stream>>>(
      X, WF32 + BF_ATW, WF32 + BF_ATB, tm_w, tm_b, ts_w, ts_b,
      out + (size_t)NB * NT, fk0[45], fk1[45]);
}

// Round 5
// 309.564 us; speedup vs baseline: 5.4961x; 1.1402x over previous
//
#include <hip/hip_runtime.h>
#include <cstdint>
#include <cstddef>

// ---------------------------------------------------------------------------
// HierarchicalNetwork: 2-layer Bayesian transformer decoder + mixture heads.
// B=512 L=128 D=128 H=4 dk=32 DFF=256 T=2048
// RNG: JAX threefry2x32 partitionable, fold_in(key(42), c) c=0..45 (verified).
// R5: decoder megakernel — one block per b runs ALL 6 stages. fp32 master X
// in registers (C-frag layout), inp_x in registers (A-frags), activations
// never touch HBM between stages. LDS: WL/Kt/Vt/Xb (34KB each) + P sliver.
// ---------------------------------------------------------------------------

#define NB   512
#define NL   128
#define ND   128
#define NH   4
#define NDFF 256
#define NT   2048
#define BL   (NB * NL)

typedef __attribute__((ext_vector_type(8))) short bf16x8;
typedef __attribute__((ext_vector_type(4))) float f32x4;

#define MFMA16(a, b, c) __builtin_amdgcn_mfma_f32_16x16x32_bf16((a), (b), (c), 0, 0, 0)

// ----------------------------- threefry2x32 --------------------------------
__host__ __device__ __forceinline__ void tf2x32(uint32_t k0, uint32_t k1,
                                                uint32_t x0, uint32_t x1,
                                                uint32_t& o0, uint32_t& o1)
{
  const uint32_t ks2 = k0 ^ k1 ^ 0x1BD11BDAu;
  x0 += k0; x1 += k1;
#define TF_RND(r) { x0 += x1; x1 = (x1 << (r)) | (x1 >> (32 - (r))); x1 ^= x0; }
  TF_RND(13) TF_RND(15) TF_RND(26) TF_RND(6)
  x0 += k1;  x1 += ks2 + 1u;
  TF_RND(17) TF_RND(29) TF_RND(16) TF_RND(24)
  x0 += ks2; x1 += k0 + 2u;
  TF_RND(13) TF_RND(15) TF_RND(26) TF_RND(6)
  x0 += k0;  x1 += k1 + 3u;
  TF_RND(17) TF_RND(29) TF_RND(16) TF_RND(24)
  x0 += k1;  x1 += ks2 + 4u;
  TF_RND(13) TF_RND(15) TF_RND(26) TF_RND(6)
  x0 += ks2; x1 += k0 + 5u;
#undef TF_RND
  o0 = x0; o1 = x1;
}

// XLA f32 erfinv (Giles). _rn ops keep XLA's separate roundings.
__device__ __forceinline__ float erfinv32(float x)
{
  float w = -log1pf(-__fmul_rn(x, x));
  float p;
  if (w < 5.0f) {
    w = w - 2.5f;
    p = 2.81022636e-08f;
    p = __fadd_rn( 3.43273939e-07f, __fmul_rn(p, w));
    p = __fadd_rn(-3.5233877e-06f,  __fmul_rn(p, w));
    p = __fadd_rn(-4.39150654e-06f, __fmul_rn(p, w));
    p = __fadd_rn( 0.00021858087f,  __fmul_rn(p, w));
    p = __fadd_rn(-0.00125372503f,  __fmul_rn(p, w));
    p = __fadd_rn(-0.00417768164f,  __fmul_rn(p, w));
    p = __fadd_rn( 0.246640727f,    __fmul_rn(p, w));
    p = __fadd_rn( 1.50140941f,     __fmul_rn(p, w));
  } else {
    w = sqrtf(w) - 3.0f;
    p = -0.000200214257f;
    p = __fadd_rn( 0.000100950558f, __fmul_rn(p, w));
    p = __fadd_rn( 0.00134934322f,  __fmul_rn(p, w));
    p = __fadd_rn(-0.00367342844f,  __fmul_rn(p, w));
    p = __fadd_rn( 0.00573950773f,  __fmul_rn(p, w));
    p = __fadd_rn(-0.0076224613f,   __fmul_rn(p, w));
    p = __fadd_rn( 0.00943887047f,  __fmul_rn(p, w));
    p = __fadd_rn( 1.00167406f,     __fmul_rn(p, w));
    p = __fadd_rn( 2.83297682f,     __fmul_rn(p, w));
  }
  return __fmul_rn(p, x);
}

__device__ __forceinline__ float bits_to_normal(uint32_t bits)
{
  const float lo = -0.99999994f;
  float f = __uint_as_float((bits >> 9) | 0x3F800000u) - 1.0f;
  float u = __fadd_rn(__fmul_rn(f, 2.0f), lo);
  u = fmaxf(lo, u);
  return __fmul_rn(1.41421356f, erfinv32(u));
}

__device__ __forceinline__ float jax_normal_idx(uint32_t k0, uint32_t k1, uint32_t idx)
{
  uint32_t o0, o1;
  tf2x32(k0, k1, 0u, idx, o0, o1);
  return bits_to_normal(o0 ^ o1);
}

__device__ __forceinline__ ushort f2bf(float f)
{
  uint32_t u = __float_as_uint(f);
  u += 0x7fffu + ((u >> 16) & 1u);
  return (ushort)(u >> 16);
}

// --------------------- fused Bayesian weight sampling ----------------------
#define SA_DECB 262144
#define SA_F1W  264192
#define SA_F1B  329728
#define SA_F2W  330240
#define SA_F2B  395776
#define SA_AW   396032
#define SA_AB   1706752
#define SA_ATW  1716992
#define SA_ATB  1717632
#define SA_TOT  1717637

#define BW_DEC  0
#define BW_F1   262144
#define BW_F2   327680
#define BW_AW   393216
#define BW_TOT  1703936

#define BF_DECB 0
#define BF_F1B  2048
#define BF_F2B  2560
#define BF_AB   2816
#define BF_ATW  13056
#define BF_ATB  13696
#define BF_TOT  13701

__global__ __launch_bounds__(256) void sample_all_kernel(
    const float* __restrict__ dec_wmu, const float* __restrict__ dec_wls,
    const float* __restrict__ dec_bmu, const float* __restrict__ dec_bls,
    const float* __restrict__ f1_wmu,  const float* __restrict__ f1_wls,
    const float* __restrict__ f1_bmu,  const float* __restrict__ f1_bls,
    const float* __restrict__ f2_wmu,  const float* __restrict__ f2_wls,
    const float* __restrict__ f2_bmu,  const float* __restrict__ f2_bls,
    const float* __restrict__ a_wmu,   const float* __restrict__ a_wls,
    const float* __restrict__ a_bmu,   const float* __restrict__ a_bls,
    const float* __restrict__ at_wmu,  const float* __restrict__ at_wls,
    const float* __restrict__ at_bmu,  const float* __restrict__ at_bls,
    ushort* __restrict__ wbf, float* __restrict__ wf32)
{
  const int i = blockIdx.x * 256 + threadIdx.x;
  if (i >= SA_TOT) return;
  const float* mu; const float* ls;
  uint32_t c, idx;
  int bf_dst = -1, f32_dst = -1;
  if (i < SA_DECB) {
    int s = i >> 14;
    mu = dec_wmu + i; ls = dec_wls + i;
    c = 2u * s + (s >= 8 ? 4u : 0u); idx = (uint32_t)(i & 16383);
    bf_dst = BW_DEC + i;
  } else if (i < SA_F1W) {
    int t = i - SA_DECB; int s = t >> 7;
    mu = dec_bmu + t; ls = dec_bls + t;
    c = 2u * s + 1u + (s >= 8 ? 4u : 0u); idx = (uint32_t)(t & 127);
    f32_dst = BF_DECB + t;
  } else if (i < SA_F1B) {
    int t = i - SA_F1W; int s = t >> 15;
    mu = f1_wmu + t; ls = f1_wls + t;
    c = 16u + 20u * s; idx = (uint32_t)(t & 32767);
    bf_dst = BW_F1 + t;
  } else if (i < SA_F2W) {
    int t = i - SA_F1B; int s = t >> 8;
    mu = f1_bmu + t; ls = f1_bls + t;
    c = 17u + 20u * s; idx = (uint32_t)(t & 255);
    f32_dst = BF_F1B + t;
  } else if (i < SA_F2B) {
    int t = i - SA_F2W; int s = t >> 15;
    mu = f2_wmu + t; ls = f2_wls + t;
    c = 18u + 20u * s; idx = (uint32_t)(t & 32767);
    bf_dst = BW_F2 + t;
  } else if (i < SA_AW) {
    int t = i - SA_F2B; int s = t >> 7;
    mu = f2_bmu + t; ls = f2_bls + t;
    c = 19u + 20u * s; idx = (uint32_t)(t & 127);
    f32_dst = BF_F2B + t;
  } else if (i < SA_AB) {
    int t = i - SA_AW;
    mu = a_wmu + t; ls = a_wls + t; c = 40u; idx = (uint32_t)t;
    bf_dst = BW_AW + t;
  } else if (i < SA_ATW) {
    int t = i - SA_AB;
    mu = a_bmu + t; ls = a_bls + t; c = 41u; idx = (uint32_t)t;
    f32_dst = BF_AB + t;
  } else if (i < SA_ATB) {
    int t = i - SA_ATW;
    mu = at_wmu + t; ls = at_wls + t; c = 42u; idx = (uint32_t)t;
    f32_dst = BF_ATW + t;
  } else {
    int t = i - SA_ATB;
    mu = at_bmu + t; ls = at_bls + t; c = 43u; idx = (uint32_t)t;
    f32_dst = BF_ATB + t;
  }
  uint32_t k0, k1;
  tf2x32(0u, 42u, 0u, c, k0, k1);
  float v = mu[0] + expf(ls[0]) * jax_normal_idx(k0, k1, idx);
  if (bf_dst >= 0) wbf[bf_dst] = f2bf(v);
  else             wf32[f32_dst] = v;
}

// ------------------------ decoder megakernel -------------------------------
// One block per b, 512 threads = 8 waves; wave w owns rows [16w,16w+16).
// C-frag: row 16w+4g+r, col 16c+r16.  A-frag: row 16w+r16, k-slice 8g.
#define STR 136

__global__ __launch_bounds__(512, 2) void decoder_mega_kernel(
    const int* __restrict__ ev, const int* __restrict__ mask,
    const float* __restrict__ emb,
    const ushort* __restrict__ WBF, const float* __restrict__ WF32,
    const float* __restrict__ lng_all, const float* __restrict__ lnb_all,
    float* __restrict__ Xh, ushort* __restrict__ Hb)
{
  __shared__ ushort WL[128][STR];
  __shared__ ushort Kt[128][STR];
  __shared__ ushort Vt[128][STR];
  __shared__ ushort Xb[128][STR];
  __shared__ ushort Ps[128][72];      // P sliver, parity double-buffered

  const int b = blockIdx.x;
  const int tid = threadIdx.x;
  const int w = tid >> 6, l = tid & 63;
  const int g = l >> 4, r16 = l & 15;
  const f32x4 zero = {0.f, 0.f, 0.f, 0.f};

  // stage a [128][128] bf16 matrix (src row stride srcStride) into dst
  auto stageS = [&](ushort (*dst)[STR], const ushort* src, int srcStride) {
#pragma unroll
    for (int it = 0; it < 4; ++it) {
      int ci = tid + it * 512;
      int row = ci >> 4, q = ci & 15;
      *(bf16x8*)&dst[row][q * 8] = *(const bf16x8*)(src + (size_t)row * srcStride + q * 8);
    }
  };

  // ---------------- init: embedding gather + positional encoding ----------
  float xreg[8][4];                       // fp32 master X, C-frag layout
  {
    int ecr[4];
#pragma unroll
    for (int r = 0; r < 4; ++r) ecr[r] = ev[b * NL + 16 * w + 4 * g + r];
#pragma unroll
    for (int c = 0; c < 8; ++c)
#pragma unroll
      for (int r = 0; r < 4; ++r) {
        float x = emb[(size_t)ecr[r] * ND + 16 * c + r16];
        xreg[c][r] = x;
        Xb[16 * w + 4 * g + r][16 * c + r16] = f2bf(x);
      }
  }
  bf16x8 inpx[4];                         // inp_x = x0 + PE, A-frag layout
  {
    const int row = 16 * w + r16;
    const int ea = ev[b * NL + row];
    const int mk = mask[b * NL + row];
    const bool even = (mk & 1) == 0;
    const float fm = (float)mk;
#pragma unroll
    for (int ks = 0; ks < 4; ++ks) {
      float4 x0 = *(const float4*)(emb + (size_t)ea * ND + 32 * ks + 8 * g);
      float4 x1 = *(const float4*)(emb + (size_t)ea * ND + 32 * ks + 8 * g + 4);
      float xs[8] = {x0.x, x0.y, x0.z, x0.w, x1.x, x1.y, x1.z, x1.w};
      bf16x8 v;
#pragma unroll
      for (int e = 0; e < 8; ++e) {
        int d = 32 * ks + 8 * g + e;
        float div = expf((float)d * (float)(-9.210340371976184 / 128.0));
        float ang = fm * div;
        float pe = even ? sinf(ang) : cosf(ang);
        v[e] = (short)f2bf(xs[e] + pe);
      }
      inpx[ks] = v;
    }
  }

#pragma unroll 1
  for (int st = 0; st < 6; ++st) {
    const int lay = st / 3, m = st - 3 * lay;
    const float* lng = lng_all + (size_t)(lay * 3 + m) * ND;
    const float* lnb = lnb_all + (size_t)(lay * 3 + m) * ND;
    f32x4 acc2[8];
#pragma unroll
    for (int c = 0; c < 8; ++c) acc2[c] = zero;
    float bo[8];

    __syncthreads();                     // prior-stage LDS reads drained
    if (m < 2) {
      // ============== attention stage (m=0 self, m=1 cross) ==============
      const int s0 = lay * 8 + m * 4;
      const ushort* W4 = WBF + BW_DEC + (size_t)s0 * 16384;
      const float*  B4 = WF32 + BF_DECB + (size_t)s0 * 128;

      // ---- Q = X @ Wq^T (held in regs) ----
      stageS(WL, W4, 128);
      __syncthreads();
      f32x4 qacc[8];
#pragma unroll
      for (int c = 0; c < 8; ++c) qacc[c] = zero;
#pragma unroll
      for (int ks = 0; ks < 4; ++ks) {
        bf16x8 a = *(const bf16x8*)&Xb[16 * w + r16][32 * ks + 8 * g];
#pragma unroll
        for (int c = 0; c < 8; ++c) {
          bf16x8 wv = *(const bf16x8*)&WL[16 * c + r16][32 * ks + 8 * g];
          qacc[c] = MFMA16(a, wv, qacc[c]);
        }
      }
      __syncthreads();
      // ---- K -> Kt ----
      stageS(WL, W4 + 16384, 128);
      __syncthreads();
      {
        f32x4 kacc[8];
#pragma unroll
        for (int c = 0; c < 8; ++c) kacc[c] = zero;
#pragma unroll
        for (int ks = 0; ks < 4; ++ks) {
          bf16x8 a = (m == 0) ? *(const bf16x8*)&Xb[16 * w + r16][32 * ks + 8 * g]
                              : inpx[ks];
#pragma unroll
          for (int c = 0; c < 8; ++c) {
            bf16x8 wv = *(const bf16x8*)&WL[16 * c + r16][32 * ks + 8 * g];
            kacc[c] = MFMA16(a, wv, kacc[c]);
          }
        }
#pragma unroll
        for (int c = 0; c < 8; ++c) {
          float kb = B4[128 + 16 * c + r16];
#pragma unroll
          for (int r = 0; r < 4; ++r)
            Kt[16 * w + 4 * g + r][16 * c + r16] = f2bf(kacc[c][r] + kb);
        }
      }
      __syncthreads();
      // ---- V -> Vt (transposed) ----
      stageS(WL, W4 + 2 * 16384, 128);
      __syncthreads();
      {
        f32x4 vacc[8];
#pragma unroll
        for (int c = 0; c < 8; ++c) vacc[c] = zero;
#pragma unroll
        for (int ks = 0; ks < 4; ++ks) {
          bf16x8 a = (m == 0) ? *(const bf16x8*)&Xb[16 * w + r16][32 * ks + 8 * g]
                              : inpx[ks];
#pragma unroll
          for (int c = 0; c < 8; ++c) {
            bf16x8 wv = *(const bf16x8*)&WL[16 * c + r16][32 * ks + 8 * g];
            vacc[c] = MFMA16(a, wv, vacc[c]);
          }
        }
#pragma unroll
        for (int c = 0; c < 8; ++c) {
          float vb = B4[256 + 16 * c + r16];
#pragma unroll
          for (int r = 0; r < 4; ++r)
            Vt[16 * c + r16][16 * w + 4 * g + r] = f2bf(vacc[c][r] + vb);
        }
      }
      __syncthreads();                   // WL(Wv) reads drained
      // ---- Q (+bias) -> WL ----
#pragma unroll
      for (int c = 0; c < 8; ++c) {
        float qb = B4[16 * c + r16];
#pragma unroll
        for (int r = 0; r < 4; ++r)
          WL[16 * w + 4 * g + r][16 * c + r16] = f2bf(qacc[c][r] + qb);
      }
      __syncthreads();                   // Q/Kt/Vt published

      // ---- attention: 4 heads, wave-local rows, P through sliver ----
      const float scale = 0.1767766952966369f;   // 1/sqrt(32)
      f32x4 oacc[4][2];
#pragma unroll
      for (int h = 0; h < 4; ++h) { oacc[h][0] = zero; oacc[h][1] = zero; }
#pragma unroll 1
      for (int h = 0; h < 4; ++h) {
        bf16x8 qa = *(const bf16x8*)&WL[16 * w + r16][32 * h + 8 * g];
        f32x4 s[8];
#pragma unroll
        for (int c = 0; c < 8; ++c) {
          bf16x8 kv = *(const bf16x8*)&Kt[16 * c + r16][32 * h + 8 * g];
          s[c] = MFMA16(qa, kv, zero);
        }
        float pv[4][8];
#pragma unroll
        for (int r = 0; r < 4; ++r) {
          float v[8]; float mx = -1e30f;
#pragma unroll
          for (int c = 0; c < 8; ++c) { v[c] = s[c][r] * scale; mx = fmaxf(mx, v[c]); }
#pragma unroll
          for (int o = 1; o < 16; o <<= 1) mx = fmaxf(mx, __shfl_xor(mx, o));
          float sum = 0.f;
#pragma unroll
          for (int c = 0; c < 8; ++c) { v[c] = __expf(v[c] - mx); sum += v[c]; }
#pragma unroll
          for (int o = 1; o < 16; o <<= 1) sum += __shfl_xor(sum, o);
          float inv = 1.0f / sum;
#pragma unroll
          for (int c = 0; c < 8; ++c) pv[r][c] = v[c] * inv;
        }
#pragma unroll
        for (int kc = 0; kc < 4; ++kc) {
          const int po = (kc & 1) * 32;
#pragma unroll
          for (int c2 = 0; c2 < 2; ++c2)
#pragma unroll
            for (int r = 0; r < 4; ++r)
              Ps[16 * w + 4 * g + r][po + 16 * c2 + r16] = f2bf(pv[r][2 * kc + c2]);
          bf16x8 pa = *(const bf16x8*)&Ps[16 * w + r16][po + 8 * g];
#pragma unroll
          for (int cc = 0; cc < 2; ++cc) {
            bf16x8 vv = *(const bf16x8*)&Vt[32 * h + 16 * cc + r16][32 * kc + 8 * g];
            oacc[h][cc] = MFMA16(pa, vv, oacc[h][cc]);
          }
        }
      }
      __syncthreads();                   // Kt/Vt/WL cross-wave reads drained
      // ---- O -> Kt; Wo -> WL; out-proj ----
#pragma unroll
      for (int h = 0; h < 4; ++h)
#pragma unroll
        for (int cc = 0; cc < 2; ++cc)
#pragma unroll
          for (int r = 0; r < 4; ++r)
            Kt[16 * w + 4 * g + r][32 * h + 16 * cc + r16] = f2bf(oacc[h][cc][r]);
      stageS(WL, W4 + 3 * 16384, 128);
      __syncthreads();
#pragma unroll
      for (int ks = 0; ks < 4; ++ks) {
        bf16x8 a = *(const bf16x8*)&Kt[16 * w + r16][32 * ks + 8 * g];
#pragma unroll
        for (int c = 0; c < 8; ++c) {
          bf16x8 wv = *(const bf16x8*)&WL[16 * c + r16][32 * ks + 8 * g];
          acc2[c] = MFMA16(a, wv, acc2[c]);
        }
      }
#pragma unroll
      for (int c = 0; c < 8; ++c) bo[c] = B4[384 + 16 * c + r16];
    } else {
      // ========================= FFN stage =========================
      const ushort* W1 = WBF + BW_F1 + (size_t)lay * 32768;
      const ushort* W2 = WBF + BW_F2 + (size_t)lay * 32768;
      const float*  B1 = WF32 + BF_F1B + (size_t)lay * 256;
      const float*  B2 = WF32 + BF_F2B + (size_t)lay * 128;
      stageS(WL, W1, 128);
      stageS(Kt, W1 + (size_t)128 * 128, 128);
      __syncthreads();
      f32x4 acc1[16];
#pragma unroll
      for (int c = 0; c < 16; ++c) acc1[c] = zero;
#pragma unroll
      for (int ks = 0; ks < 4; ++ks) {
        bf16x8 a = *(const bf16x8*)&Xb[16 * w + r16][32 * ks + 8 * g];
#pragma unroll
        for (int c = 0; c < 8; ++c) {
          bf16x8 w1v = *(const bf16x8*)&WL[16 * c + r16][32 * ks + 8 * g];
          acc1[c] = MFMA16(a, w1v, acc1[c]);
          bf16x8 w2v = *(const bf16x8*)&Kt[16 * c + r16][32 * ks + 8 * g];
          acc1[8 + c] = MFMA16(a, w2v, acc1[8 + c]);
        }
      }
      __syncthreads();                   // W1 reads drained
      // H1 = relu(+bias) -> WL (cols 0-127) / Kt (cols 128-255)
#pragma unroll
      for (int c = 0; c < 16; ++c) {
        float bb = B1[16 * c + r16];
#pragma unroll
        for (int r = 0; r < 4; ++r) {
          float o = fmaxf(acc1[c][r] + bb, 0.f);
          if (c < 8) WL[16 * w + 4 * g + r][16 * c + r16] = f2bf(o);
          else       Kt[16 * w + 4 * g + r][16 * (c - 8) + r16] = f2bf(o);
        }
      }
      stageS(Vt, W2, 256);               // W2 k-cols 0-127
      __syncthreads();
#pragma unroll
      for (int ks = 0; ks < 4; ++ks) {
        bf16x8 a = *(const bf16x8*)&WL[16 * w + r16][32 * ks + 8 * g];
#pragma unroll
        for (int c = 0; c < 8; ++c) {
          bf16x8 wv = *(const bf16x8*)&Vt[16 * c + r16][32 * ks + 8 * g];
          acc2[c] = MFMA16(a, wv, acc2[c]);
        }
      }
      __syncthreads();                   // Vt(W2a) reads drained
      stageS(Vt, W2 + 128, 256);         // W2 k-cols 128-255
      __syncthreads();
#pragma unroll
      for (int ks = 0; ks < 4; ++ks) {
        bf16x8 a = *(const bf16x8*)&Kt[16 * w + r16][32 * ks + 8 * g];
#pragma unroll
        for (int c = 0; c < 8; ++c) {
          bf16x8 wv = *(const bf16x8*)&Vt[16 * c + r16][32 * ks + 8 * g];
          acc2[c] = MFMA16(a, wv, acc2[c]);
        }
      }
#pragma unroll
      for (int c = 0; c < 8; ++c) bo[c] = B2[16 * c + r16];
    }

    // ---------------- shared epilogue: residual + LayerNorm ----------------
    float gg[8], lb[8];
#pragma unroll
    for (int c = 0; c < 8; ++c) { gg[c] = lng[16 * c + r16]; lb[c] = lnb[16 * c + r16]; }
#pragma unroll
    for (int r = 0; r < 4; ++r) {
      float xv[8];
#pragma unroll
      for (int c = 0; c < 8; ++c) xv[c] = acc2[c][r] + bo[c] + xreg[c][r];
      float s = 0.f;
#pragma unroll
      for (int c = 0; c < 8; ++c) s += xv[c];
#pragma unroll
      for (int o = 1; o < 16; o <<= 1) s += __shfl_xor(s, o);
      float mean = s * (1.0f / 128.0f);
      float q = 0.f;
#pragma unroll
      for (int c = 0; c < 8; ++c) { float d = xv[c] - mean; q += d * d; }
#pragma unroll
      for (int o = 1; o < 16; o <<= 1) q += __shfl_xor(q, o);
      float inv = 1.0f / sqrtf(q * (1.0f / 128.0f) + 1e-5f);
#pragma unroll
      for (int c = 0; c < 8; ++c) {
        float o = (xv[c] - mean) * inv * gg[c] + lb[c];
        xreg[c][r] = o;
        Xb[16 * w + 4 * g + r][16 * c + r16] = f2bf(o);
      }
    }
  }

  // ---- final: h = x[:,0,:] (row 0) ----
  if (w == 0 && g == 0) {
#pragma unroll
    for (int c = 0; c < 8; ++c) {
      Xh[(size_t)b * ND + 16 * c + r16] = xreg[c][0];
      Hb[(size_t)b * ND + 16 * c + r16] = f2bf(xreg[c][0]);
    }
  }
}

// ------------------------------ head GEMM ----------------------------------
template<int WFP32>
__global__ __launch_bounds__(256) void head_gemm(
    const ushort* __restrict__ A,
    const ushort* __restrict__ Wb16, const float* __restrict__ Wf32,
    const float* __restrict__ bias, float* __restrict__ C, int ldc)
{
  __shared__ char smem[128 * 132 * 4];
  ushort (*Wl)[STR] = (ushort(*)[STR])smem;
  float  (*Cl)[132] = (float(*)[132])smem;

  const int tid = threadIdx.x;
  const int bn = blockIdx.x * 128;
  const int bm = blockIdx.y * 128;
  const int w = tid >> 6, l = tid & 63;
  const int r16 = l & 15, g = l >> 4;
  const f32x4 zero = {0.f, 0.f, 0.f, 0.f};

#pragma unroll
  for (int it = 0; it < 8; ++it) {
    int ci = tid + it * 256;
    int row = ci >> 4, q = ci & 15;
    if (WFP32) {
      float4 v0 = *(const float4*)(Wf32 + (size_t)(bn + row) * 128 + q * 8);
      float4 v1 = *(const float4*)(Wf32 + (size_t)(bn + row) * 128 + q * 8 + 4);
      bf16x8 o;
      o[0] = f2bf(v0.x); o[1] = f2bf(v0.y); o[2] = f2bf(v0.z); o[3] = f2bf(v0.w);
      o[4] = f2bf(v1.x); o[5] = f2bf(v1.y); o[6] = f2bf(v1.z); o[7] = f2bf(v1.w);
      *(bf16x8*)&Wl[row][q * 8] = o;
    } else {
      *(bf16x8*)&Wl[row][q * 8] =
          *(const bf16x8*)(Wb16 + (size_t)(bn + row) * 128 + q * 8);
    }
  }
  __syncthreads();

  f32x4 acc[2][8];
#pragma unroll
  for (int t = 0; t < 2; ++t)
#pragma unroll
    for (int c = 0; c < 8; ++c) acc[t][c] = zero;
#pragma unroll
  for (int ks = 0; ks < 4; ++ks) {
    bf16x8 a[2];
#pragma unroll
    for (int t = 0; t < 2; ++t)
      a[t] = *(const bf16x8*)(A + (size_t)(bm + 32 * w + 16 * t + r16) * 128
                              + 32 * ks + 8 * g);
    bf16x8 wv[8];
#pragma unroll
    for (int c = 0; c < 8; ++c)
      wv[c] = *(const bf16x8*)&Wl[16 * c + r16][32 * ks + 8 * g];
#pragma unroll
    for (int t = 0; t < 2; ++t)
#pragma unroll
      for (int c = 0; c < 8; ++c)
        acc[t][c] = MFMA16(a[t], wv[c], acc[t][c]);
  }

  float bcol[8];
#pragma unroll
  for (int c = 0; c < 8; ++c) bcol[c] = bias[bn + 16 * c + r16];
  __syncthreads();

#pragma unroll
  for (int t = 0; t < 2; ++t)
#pragma unroll
    for (int c = 0; c < 8; ++c)
#pragma unroll
      for (int r = 0; r < 4; ++r)
        Cl[32 * w + 16 * t + 4 * g + r][16 * c + r16] = acc[t][c][r] + bcol[c];
  __syncthreads();
#pragma unroll
  for (int i = 0; i < 16; ++i) {
    int ci = l + 64 * i;
    int row = 32 * w + (ci >> 5), q = ci & 31;
    float4 v = *(const float4*)&Cl[row][4 * q];
    *(float4*)(C + (size_t)(bm + row) * ldc + bn + 4 * q) = v;
  }
}

// ------------------------------ event head ---------------------------------
__global__ __launch_bounds__(256) void event_head_kernel(
    const float* __restrict__ LA, const float* __restrict__ MB,
    const float* __restrict__ SB, float* __restrict__ out,
    uint32_t k0, uint32_t k1)
{
  int i = blockIdx.x * 256 + threadIdx.x;
  if (i >= NB * NT) return;
  int b = i >> 11, t = i & (NT - 1);
  size_t base = (size_t)b * (5 * NT) + t;
  float lg[5];
  float mx = -1e30f;
#pragma unroll
  for (int k = 0; k < 5; ++k) { lg[k] = LA[base + (size_t)k * NT]; mx = fmaxf(mx, lg[k]); }
  float se = 0.f;
#pragma unroll
  for (int k = 0; k < 5; ++k) { lg[k] = expf(lg[k] - mx); se += lg[k]; }
  float inv = 1.0f / se;
  float acc = 0.f;
#pragma unroll
  for (int k = 0; k < 5; ++k) {
    float nz = jax_normal_idx(k0, k1, (uint32_t)((b * 5 + k) * NT + t));
    float mean = MB[base + (size_t)k * NT];
    float sd   = expf(SB[base + (size_t)k * NT]);
    acc += (lg[k] * inv) * (mean + sd * nz);
  }
  out[i] = acc;
}

// ------------------------------- time head ---------------------------------
__global__ __launch_bounds__(64) void time_head_kernel(
    const float* __restrict__ Xh, const float* __restrict__ atw,
    const float* __restrict__ atb, const float* __restrict__ tmw,
    const float* __restrict__ tmb, const float* __restrict__ tsw,
    const float* __restrict__ tsb, float* __restrict__ out,
    uint32_t k0, uint32_t k1)
{
  const int b = blockIdx.x;
  const int l = threadIdx.x;
  const float* h = Xh + (size_t)b * ND;
  const float h0 = h[l], h1 = h[l + 64];
  float lg[5], tm[5], tsl[5];
#pragma unroll
  for (int k = 0; k < 5; ++k) {
    float s0 = fmaf(h0, atw[k * ND + l], h1 * atw[k * ND + l + 64]);
    float s1 = fmaf(h0, tmw[k * ND + l], h1 * tmw[k * ND + l + 64]);
    float s2 = fmaf(h0, tsw[k * ND + l], h1 * tsw[k * ND + l + 64]);
#pragma unroll
    for (int o = 32; o; o >>= 1) {
      s0 += __shfl_xor(s0, o);
      s1 += __shfl_xor(s1, o);
      s2 += __shfl_xor(s2, o);
    }
    lg[k] = s0 + atb[k]; tm[k] = s1 + tmb[k]; tsl[k] = s2 + tsb[k];
  }
  if (l == 0) {
    float mx = lg[0];
    for (int k = 1; k < 5; ++k) mx = fmaxf(mx, lg[k]);
    float se = 0.f;
    for (int k = 0; k < 5; ++k) { lg[k] = expf(lg[k] - mx); se += lg[k]; }
    float acc = 0.f;
    for (int k = 0; k < 5; ++k) {
      float nz = jax_normal_idx(k0, k1, (uint32_t)(b * 5 + k));
      acc += (lg[k] / se) * (tm[k] + expf(tsl[k]) * nz);
    }
    out[b] = acc;
  }
}

// ------------------------------ host driver --------------------------------
extern "C" void kernel_launch(void* const* d_in, const int* in_sizes, int n_in,
                              void* d_out, int out_size, void* d_ws, size_t ws_size,
                              hipStream_t stream)
{
  (void)in_sizes; (void)n_in; (void)out_size; (void)ws_size;

  const int*   ev      = (const int*)d_in[0];
  const int*   mask    = (const int*)d_in[2];
  const float* emb     = (const float*)d_in[4];
  const float* dec_wmu = (const float*)d_in[5];
  const float* dec_wls = (const float*)d_in[6];
  const float* dec_bmu = (const float*)d_in[7];
  const float* dec_bls = (const float*)d_in[8];
  const float* f1_wmu  = (const float*)d_in[9];
  const float* f1_wls  = (const float*)d_in[10];
  const float* f1_bmu  = (const float*)d_in[11];
  const float* f1_bls  = (const float*)d_in[12];
  const float* f2_wmu  = (const float*)d_in[13];
  const float* f2_wls  = (const float*)d_in[14];
  const float* f2_bmu  = (const float*)d_in[15];
  const float* f2_bls  = (const float*)d_in[16];
  const float* ln_g    = (const float*)d_in[17];
  const float* ln_b    = (const float*)d_in[18];
  const float* a_wmu   = (const float*)d_in[19];
  const float* a_wls   = (const float*)d_in[20];
  const float* a_bmu   = (const float*)d_in[21];
  const float* a_bls   = (const float*)d_in[22];
  const float* at_wmu  = (const float*)d_in[23];
  const float* at_wls  = (const float*)d_in[24];
  const float* at_bmu  = (const float*)d_in[25];
  const float* at_bls  = (const float*)d_in[26];
  const float* em_w    = (const float*)d_in[27];
  const float* em_b    = (const float*)d_in[28];
  const float* es_w    = (const float*)d_in[29];
  const float* es_b    = (const float*)d_in[30];
  const float* tm_w    = (const float*)d_in[31];
  const float* tm_b    = (const float*)d_in[32];
  const float* ts_w    = (const float*)d_in[33];
  const float* ts_b    = (const float*)d_in[34];

  float* ws = (float*)d_ws;
  const size_t HN = (size_t)NB * 5 * NT;     // 5,242,880
  float*  LA   = ws;
  float*  MBo  = LA + HN;
  float*  SBo  = MBo + HN;
  ushort* WBF  = (ushort*)(SBo + HN);        // sampled weights bf16
  float*  WF32 = SBo + HN + BW_TOT / 2;      // sampled biases fp32
  ushort* Hb   = (ushort*)(WF32 + BF_TOT + 3);   // 16B-aligned bf16 h
  float*  Xh   = (float*)(Hb + (size_t)NB * ND); // fp32 h

  uint32_t fk0[46], fk1[46];
  for (uint32_t c = 0; c < 46; ++c) tf2x32(0u, 42u, 0u, c, fk0[c], fk1[c]);

  sample_all_kernel<<<dim3((SA_TOT + 255) / 256), dim3(256), 0, stream>>>(
      dec_wmu, dec_wls, dec_bmu, dec_bls,
      f1_wmu, f1_wls, f1_bmu, f1_bls,
      f2_wmu, f2_wls, f2_bmu, f2_bls,
      a_wmu, a_wls, a_bmu, a_bls,
      at_wmu, at_wls, at_bmu, at_bls, WBF, WF32);

  decoder_mega_kernel<<<dim3(NB), dim3(512), 0, stream>>>(
      ev, mask, emb, WBF, WF32, ln_g, ln_b, Xh, Hb);

  head_gemm<0><<<dim3(80, 4), dim3(256), 0, stream>>>(
      Hb, WBF + BW_AW, nullptr, WF32 + BF_AB, LA, 5 * NT);
  head_gemm<1><<<dim3(80, 4), dim3(256), 0, stream>>>(
      Hb, nullptr, em_w, em_b, MBo, 5 * NT);
  head_gemm<1><<<dim3(80, 4), dim3(256), 0, stream>>>(
      Hb, nullptr, es_w, es_b, SBo, 5 * NT);

  float* out = (float*)d_out;
  event_head_kernel<<<dim3((NB * NT) / 256), dim3(256), 0, stream>>>(
      LA, MBo, SBo, out, fk0[44], fk1[44]);
  time_head_kernel<<<dim3(NB), dim3(64), 0, stream>>>(
      Xh, WF32 + BF_ATW, WF32 + BF_ATB, tm_w, tm_b, ts_w, ts_b,
      out + (size_t)NB * NT, fk0[45], fk1[45]);
}